// Round 1
// 1545.511 us; speedup vs baseline: 1.0651x; 1.0651x over previous
//
#include <hip/hip_runtime.h>
#include <hip/hip_bf16.h>
#include <math.h>

#define T_N   262144
#define NSTEP (T_N - 1)   // 262143 scan steps
#define CS    256         // chunk size
#define NC    1024        // number of chunks (NC*CS >= NSTEP)
#define NG    32          // groups of chunks (NC/32)

// output layout (floats): log_alpha(T,16) log_beta(T,16) log_trs(T-1,256) log_pis(T,16) entropy(T-1,16)
#define OFF_A   ((size_t)0)
#define OFF_B   ((size_t)4194304)
#define OFF_LTR ((size_t)8388608)
#define OFF_LPI ((size_t)75497216)
#define OFF_ENT ((size_t)79691520)

// workspace layout (floats)
#define WS_TR0  ((size_t)0)
#define WS_M    ((size_t)64)
#define WS_LP   (WS_M  + (size_t)NC*256)
#define WS_LS   (WS_LP + (size_t)NC*256)
#define WS_GT   (WS_LS + (size_t)NC*256)
#define WS_GP   (WS_GT + (size_t)NG*256)
#define WS_GSU  (WS_GP + (size_t)NG*256)
#define WS_PREF (WS_GSU + (size_t)NG*256)
#define WS_SUF  (WS_PREF + (size_t)NC*256)
#define WS_WP   (WS_SUF  + (size_t)NC*256)   // packed bf16 weights start here (as ushort)

// packed-weight offsets (ushort units)
#define O_pW1h 0
#define O_pW1l 16384
#define O_pW2h 32768
#define O_pW2l 98304
#define O_pW3h 163840
#define O_pW3l 196608
#define O_oW1h 229376
#define O_oW1l 245760
#define O_oW2h 262144
#define O_oW2l 327680
#define O_oW3h 393216
#define O_oW3l 462848

#define NEGINF (-1e30f)

typedef unsigned short ushort_t;
typedef short s8v __attribute__((ext_vector_type(8)));
typedef float f4v __attribute__((ext_vector_type(4)));

__device__ __forceinline__ ushort_t f2bf_rn(float f) {
  __hip_bfloat16 h = __float2bfloat16(f);
  union { __hip_bfloat16 b; ushort_t u; } cv; cv.b = h; return cv.u;
}
__device__ __forceinline__ float us2f(ushort_t u) {
  return __uint_as_float(((unsigned)u) << 16);
}
__device__ __forceinline__ void split_bf(float x, ushort_t& h, ushort_t& lo) {
  unsigned u = __float_as_uint(x);
  h = (ushort_t)(u >> 16);
  lo = f2bf_rn(x - __uint_as_float(u & 0xffff0000u));
}

// ----------------------------------------------------------- weight packing ---
// layout: idx = ((ks*NT + nt)*64 + lane)*8 + j  maps  B[k=ks*32+(lane>>4)*8+j][n=nt*16+(lane&15)]
__global__ void k_pack(const float* __restrict__ W, int KN, int NT, int N,
                       ushort_t* __restrict__ dh, ushort_t* __restrict__ dl)
{
  int idx = blockIdx.x * 256 + threadIdx.x;
  if (idx >= KN) return;
  int j  = idx & 7;
  int l  = (idx >> 3) & 63;
  int t2 = idx >> 9;
  int nt = t2 % NT;
  int ks = t2 / NT;
  int k = ks * 32 + (l >> 4) * 8 + j;
  int n = nt * 16 + (l & 15);
  float x = W[(size_t)k * N + n];
  unsigned u = __float_as_uint(x);
  dh[idx] = (ushort_t)(u >> 16);
  dl[idx] = f2bf_rn(x - __uint_as_float(u & 0xffff0000u));
}

// ---------------------------------------------------------------- K1: MLPs ---

#define LDX 72
#define LDH 264

template<int KS, int NTC>
__device__ __forceinline__ void run_layer(const ushort_t* Ah, const ushort_t* Al, int lda,
    const ushort_t* __restrict__ Bh, const ushort_t* __restrict__ Bl, int ntt, int nt0,
    const float* __restrict__ bias, int lane, f4v (&acc)[2][NTC])
{
#pragma unroll
  for (int mt = 0; mt < 2; mt++)
#pragma unroll
    for (int nt = 0; nt < NTC; nt++) {
      float b = bias[(nt0 + nt) * 16 + (lane & 15)];
      acc[mt][nt] = (f4v){b, b, b, b};
    }
  for (int ks = 0; ks < KS; ks++) {
    s8v ah[2], al[2];
#pragma unroll
    for (int mt = 0; mt < 2; mt++) {
      const ushort_t* p = Ah + (size_t)(mt * 16 + (lane & 15)) * lda + ks * 32 + (lane >> 4) * 8;
      ah[mt] = *(const s8v*)p;
      const ushort_t* q = Al + (size_t)(mt * 16 + (lane & 15)) * lda + ks * 32 + (lane >> 4) * 8;
      al[mt] = *(const s8v*)q;
    }
#pragma unroll
    for (int nt = 0; nt < NTC; nt++) {
      size_t bo = ((size_t)(ks * ntt + nt0 + nt) * 64 + lane) * 8;
      s8v bh = *(const s8v*)(Bh + bo);
      s8v bl = *(const s8v*)(Bl + bo);
#pragma unroll
      for (int mt = 0; mt < 2; mt++) {
        acc[mt][nt] = __builtin_amdgcn_mfma_f32_16x16x32_bf16(ah[mt], bh, acc[mt][nt], 0, 0, 0);
        acc[mt][nt] = __builtin_amdgcn_mfma_f32_16x16x32_bf16(al[mt], bh, acc[mt][nt], 0, 0, 0);
        acc[mt][nt] = __builtin_amdgcn_mfma_f32_16x16x32_bf16(ah[mt], bl, acc[mt][nt], 0, 0, 0);
      }
    }
  }
}

__device__ __forceinline__ void store_act(f4v (&acc)[2][4], int nt0, int lane,
                                          ushort_t* Hh, ushort_t* Hl)
{
#pragma unroll
  for (int mt = 0; mt < 2; mt++)
#pragma unroll
    for (int nt = 0; nt < 4; nt++)
#pragma unroll
      for (int r = 0; r < 4; r++) {
        float v = fmaxf(acc[mt][nt][r], 0.f);
        ushort_t h, lo; split_bf(v, h, lo);
        int row = mt * 16 + (lane >> 4) * 4 + r;
        int n = (nt0 + nt) * 16 + (lane & 15);
        Hh[row * LDH + n] = h;
        Hl[row * LDH + n] = lo;
      }
}

__launch_bounds__(256, 3)
__global__ void k_mlp2(const float* __restrict__ s_array, const float* __restrict__ a_array,
                       const float* __restrict__ pb1, const float* __restrict__ pb2,
                       const float* __restrict__ pb3, const float* __restrict__ ob1,
                       const float* __restrict__ ob2, const float* __restrict__ ob3,
                       const float* __restrict__ oW3, const float* __restrict__ als,
                       const ushort_t* __restrict__ wp, float* out, float* ws)
{
  __shared__ ushort_t Xh[32 * LDX], Xl[32 * LDX];
  __shared__ ushort_t Hh[32 * LDH], Hl[32 * LDH];
  __shared__ float tr0s[16];
  const int tid = threadIdx.x;
  const int lane = tid & 63;
  const int w = tid >> 6;
  const size_t row0 = (size_t)blockIdx.x * 32;

  { // stage X (32 rows x 64) into LDS split-bf16, A-frag friendly
    const float4* src = (const float4*)(s_array + row0 * 64);
    for (int f = tid; f < 512; f += 256) {
      float4 v = src[f];
      int r = f >> 4, c = (f & 15) * 4;
      ushort_t h0, l0, h1, l1, h2, l2, h3, l3;
      split_bf(v.x, h0, l0); split_bf(v.y, h1, l1);
      split_bf(v.z, h2, l2); split_bf(v.w, h3, l3);
      ushort4 hh = make_ushort4(h0, h1, h2, h3);
      ushort4 ll = make_ushort4(l0, l1, l2, l3);
      *(ushort4*)&Xh[r * LDX + c] = hh;
      *(ushort4*)&Xl[r * LDX + c] = ll;
    }
  }
  __syncthreads();

  f4v acc[2][4];

  // ===== option net =====
  run_layer<2, 4>(Xh, Xl, LDX, wp + O_oW1h, wp + O_oW1l, 16, w * 4, ob1, lane, acc);
  store_act(acc, w * 4, lane, Hh, Hl);
  __syncthreads();
  run_layer<8, 4>(Hh, Hl, LDH, wp + O_oW2h, wp + O_oW2l, 16, w * 4, ob2, lane, acc);
  __syncthreads();
  store_act(acc, w * 4, lane, Hh, Hl);
  __syncthreads();
  run_layer<8, 4>(Hh, Hl, LDH, wp + O_oW3h, wp + O_oW3l, 17, w * 4, ob3, lane, acc);

  // log-softmax + entropy epilogue (groups == 16-col tiles)
#pragma unroll
  for (int mt = 0; mt < 2; mt++)
#pragma unroll
    for (int nt = 0; nt < 4; nt++) {
      int g = w * 4 + nt;
      int col = lane & 15;
#pragma unroll
      for (int r = 0; r < 4; r++) {
        size_t t = row0 + mt * 16 + (lane >> 4) * 4 + r;
        float x = acc[mt][nt][r];
        float m = x;
        m = fmaxf(m, __shfl_xor(m, 1, 64));
        m = fmaxf(m, __shfl_xor(m, 2, 64));
        m = fmaxf(m, __shfl_xor(m, 4, 64));
        m = fmaxf(m, __shfl_xor(m, 8, 64));
        float s = __expf(x - m);
        s += __shfl_xor(s, 1, 64);
        s += __shfl_xor(s, 2, 64);
        s += __shfl_xor(s, 4, 64);
        s += __shfl_xor(s, 8, 64);
        float L = m + __logf(s);
        float v = x - L;
        float e = -v * __expf(v);
        e += __shfl_xor(e, 1, 64);
        e += __shfl_xor(e, 2, 64);
        e += __shfl_xor(e, 4, 64);
        e += __shfl_xor(e, 8, 64);
        if (t >= 1) {
          out[OFF_LTR + (t - 1) * 256 + (size_t)g * 16 + col] = v;
          if (col == 0) out[OFF_ENT + (t - 1) * 16 + g] = e;
        }
      }
    }

  // log_tr0: row 0's 17th group (block 0 only); H still holds option act2
  if (blockIdx.x == 0 && tid < 16) {
    float a = ob3[256 + tid];
    for (int k2 = 0; k2 < 256; k2++) {
      float hv = us2f(Hh[k2]) + us2f(Hl[k2]);
      a = fmaf(hv, oW3[(size_t)k2 * 272 + 256 + tid], a);
    }
    tr0s[tid] = a;
  }
  __syncthreads();   // also guards H reads (option L3) vs policy L1 writes
  if (blockIdx.x == 0 && tid == 0) {
    float m = NEGINF;
    for (int j = 0; j < 16; j++) m = fmaxf(m, tr0s[j]);
    float s = 0.f;
    for (int j = 0; j < 16; j++) s += __expf(tr0s[j] - m);
    float L = m + __logf(s);
    for (int j = 0; j < 16; j++) ws[WS_TR0 + j] = tr0s[j] - L;
  }

  // ===== policy net =====
  run_layer<2, 4>(Xh, Xl, LDX, wp + O_pW1h, wp + O_pW1l, 16, w * 4, pb1, lane, acc);
  store_act(acc, w * 4, lane, Hh, Hl);
  __syncthreads();
  run_layer<8, 4>(Hh, Hl, LDH, wp + O_pW2h, wp + O_pW2l, 16, w * 4, pb2, lane, acc);
  __syncthreads();
  store_act(acc, w * 4, lane, Hh, Hl);
  __syncthreads();
  f4v pacc[2][2];
  run_layer<8, 2>(Hh, Hl, LDH, wp + O_pW3h, wp + O_pW3l, 8, w * 2, pb3, lane, pacc);

  // gaussian log-prob epilogue
  float istd[8];
  float Kc = -8.0f * 0.91893853320467274f;
#pragma unroll
  for (int a = 0; a < 8; a++) {
    float l = -5.0f + 3.5f * (tanhf(als[a]) + 1.0f);
    istd[a] = __expf(-l);
    Kc -= l;
  }
  int aIdx = lane & 7;
#pragma unroll
  for (int mt = 0; mt < 2; mt++)
#pragma unroll
    for (int nt = 0; nt < 2; nt++) {
      int col = (w * 2 + nt) * 16 + (lane & 15);
      int c = col >> 3;
#pragma unroll
      for (int r = 0; r < 4; r++) {
        size_t t = row0 + mt * 16 + (lane >> 4) * 4 + r;
        float mean = fminf(10.f, fmaxf(-10.f, pacc[mt][nt][r]));
        float av = a_array[t * 8 + aIdx];
        float z = (av - mean) * istd[aIdx];
        float q = z * z;
        q += __shfl_xor(q, 1, 64);
        q += __shfl_xor(q, 2, 64);
        q += __shfl_xor(q, 4, 64);
        if ((lane & 7) == 0) out[OFF_LPI + t * 16 + c] = -0.5f * q + Kc;
      }
    }
}

// ------------------------------------------------- K2: per-chunk log-matmul ---
// Pipelined rewrite: depth-2 register prefetch of the next tr-rows/lpi, transposed
// As staging (stride 20 -> 16B-aligned rows, <=2-way banks), double-buffered LDS,
// ONE barrier per step. Prefetch rows beyond the chunk stay inside the out buffer
// (LTR is followed by LPI/ENT), so no guards needed.

#define LDA 20

__launch_bounds__(256, 4)
__global__ void k_compose(const float* __restrict__ out, float* __restrict__ ws)
{
  __shared__ float AsT[2][16 * LDA] __attribute__((aligned(16)));  // AsT[b][k*LDA+j] = As[j][k]
  __shared__ float Mb[2][16 * 16] __attribute__((aligned(16)));    // Mb[b][i*16+k]
  __shared__ float Lsb[2][16];
  const int tid = threadIdx.x;
  const int i = tid >> 4, k = tid & 15;
  const int c = blockIdx.x;
  long long e0 = (long long)c * CS;
  long long e1 = e0 + CS; if (e1 > NSTEP) e1 = NSTEP;

  float a1, l1;
  {
    float a0 = out[OFF_LTR + (size_t)e0 * 256 + tid];
    AsT[0][k * LDA + i] = a0;
    if (tid < 16) Lsb[0][tid] = out[OFF_LPI + (size_t)(e0 + 1) * 16 + tid];
    Mb[0][tid] = (i == k) ? 0.f : NEGINF;
    a1 = out[OFF_LTR + (size_t)(e0 + 1) * 256 + tid];
    l1 = (tid < 16) ? out[OFF_LPI + (size_t)(e0 + 2) * 16 + tid] : 0.f;
  }
  __syncthreads();

  int cur = 0;
  float last = NEGINF;
  for (long long e = e0; e < e1; e++) {
    // prefetch step e+2 (in-buffer even past the chunk/array end)
    float a2 = out[OFF_LTR + (size_t)(e + 2) * 256 + tid];
    float l2 = (tid < 16) ? out[OFF_LPI + (size_t)(e + 3) * 16 + tid] : 0.f;

    // compute step e from buffers [cur]
    float v[16];
    {
      const float4* M4 = (const float4*)&Mb[cur][i * 16];
      const float4* A4 = (const float4*)&AsT[cur][k * LDA];
#pragma unroll
      for (int t = 0; t < 4; t++) {
        float4 a = M4[t], b = A4[t];
        v[4 * t + 0] = a.x + b.x; v[4 * t + 1] = a.y + b.y;
        v[4 * t + 2] = a.z + b.z; v[4 * t + 3] = a.w + b.w;
      }
    }
    float m = NEGINF;
#pragma unroll
    for (int j = 0; j < 16; j++) m = fmaxf(m, v[j]);
    float s = 0.f;
#pragma unroll
    for (int j = 0; j < 16; j++) s += __expf(v[j] - m);
    last = m + __logf(s) + Lsb[cur][k];

    // stage step e+1 + new M into buffers [cur^1] (no conflict with [cur] readers)
    AsT[cur ^ 1][k * LDA + i] = a1;
    if (tid < 16) Lsb[cur ^ 1][tid] = l1;
    Mb[cur ^ 1][tid] = last;
    __syncthreads();
    a1 = a2; l1 = l2;
    cur ^= 1;
  }
  ws[WS_M + (size_t)c * 256 + tid] = last;
}

// -------------------------------- K3/K4: group-level matrix prefix & suffix ---
// Pipelined: next row prefetched into registers before the barrier-synced update.

__launch_bounds__(256, 4)
__global__ void k_scan_mats(const float* __restrict__ src, float* __restrict__ preDst,
                            float* __restrict__ sufDst, float* __restrict__ totDst)
{
  __shared__ float Cur[16 * 17];
  const int tid = threadIdx.x, i = tid >> 4, k = tid & 15;
  const int g = blockIdx.x;
  const float* S = src + (size_t)g * 32 * 256;
  const float id = (i == k) ? 0.f : NEGINF;

  float rv[16], rn[16];
  Cur[i * 17 + k] = id;
#pragma unroll
  for (int j = 0; j < 16; j++) rv[j] = S[j * 16 + k];   // row 0, column k
  __syncthreads();
  for (int r = 0; r < 32; r++) {
    preDst[((size_t)g * 32 + r) * 256 + tid] = Cur[i * 17 + k];
    int rp = (r + 1 < 32) ? r + 1 : 31;                 // clamp: harmless re-read
#pragma unroll
    for (int j = 0; j < 16; j++) rn[j] = S[(size_t)rp * 256 + j * 16 + k];
    float v[16]; float m = NEGINF;
#pragma unroll
    for (int j = 0; j < 16; j++) { v[j] = Cur[i * 17 + j] + rv[j]; m = fmaxf(m, v[j]); }
    float s = 0.f;
#pragma unroll
    for (int j = 0; j < 16; j++) s += __expf(v[j] - m);
    float res = m + __logf(s);
    __syncthreads();
    Cur[i * 17 + k] = res;
    __syncthreads();
#pragma unroll
    for (int j = 0; j < 16; j++) rv[j] = rn[j];
  }
  if (totDst) totDst[(size_t)g * 256 + tid] = Cur[i * 17 + k];
  __syncthreads();
  Cur[i * 17 + k] = id;
#pragma unroll
  for (int j = 0; j < 16; j++) rv[j] = S[(size_t)31 * 256 + i * 16 + j];  // row 31, row i
  __syncthreads();
  for (int r = 31; r >= 0; r--) {
    sufDst[((size_t)g * 32 + r) * 256 + tid] = Cur[i * 17 + k];
    int rp = (r > 0) ? r - 1 : 0;                       // clamp: avoids OOB at r==0
#pragma unroll
    for (int j = 0; j < 16; j++) rn[j] = S[(size_t)rp * 256 + i * 16 + j];
    float v[16]; float m = NEGINF;
#pragma unroll
    for (int j = 0; j < 16; j++) { v[j] = rv[j] + Cur[j * 17 + k]; m = fmaxf(m, v[j]); }
    float s = 0.f;
#pragma unroll
    for (int j = 0; j < 16; j++) s += __expf(v[j] - m);
    float res = m + __logf(s);
    __syncthreads();
    Cur[i * 17 + k] = res;
    __syncthreads();
#pragma unroll
    for (int j = 0; j < 16; j++) rv[j] = rn[j];
  }
}

// ------------------------- K5: chunk-level exclusive prefix/suffix matrices ---

__launch_bounds__(256, 4)
__global__ void k_combine(float* ws)
{
  const int tid = threadIdx.x, i = tid >> 4, k = tid & 15;
  const int c = blockIdx.x, g = c >> 5;
  {
    const float* GP = ws + WS_GP + (size_t)g * 256;
    const float* LP = ws + WS_LP + (size_t)c * 256;
    float v[16]; float m = NEGINF;
#pragma unroll
    for (int j = 0; j < 16; j++) { v[j] = GP[i * 16 + j] + LP[j * 16 + k]; m = fmaxf(m, v[j]); }
    float s = 0.f;
#pragma unroll
    for (int j = 0; j < 16; j++) s += __expf(v[j] - m);
    ws[WS_PREF + (size_t)c * 256 + tid] = m + __logf(s);
  }
  {
    const float* LSu = ws + WS_LS + (size_t)c * 256;
    const float* GSu = ws + WS_GSU + (size_t)g * 256;
    float v[16]; float m = NEGINF;
#pragma unroll
    for (int j = 0; j < 16; j++) { v[j] = LSu[i * 16 + j] + GSu[j * 16 + k]; m = fmaxf(m, v[j]); }
    float s = 0.f;
#pragma unroll
    for (int j = 0; j < 16; j++) s += __expf(v[j] - m);
    ws[WS_SUF + (size_t)c * 256 + tid] = m + __logf(s);
  }
}

// --------------------------------------------------------- K6: chunk replay ---
// Pipelined rewrite: depth-2 register prefetch of tr/lpi in both waves; beta's
// row reads vectorized to float4. Out-of-range prefetches stay inside the out
// allocation (forward spill lands in LPI/ENT; backward spill stays >= OFF_B).

__device__ __forceinline__ void lse_combine(float& m, float& s, int mask)
{
  float m2 = __shfl_xor(m, mask, 64);
  float s2 = __shfl_xor(s, mask, 64);
  float M_ = fmaxf(m, m2);
  s = s * __expf(m - M_) + s2 * __expf(m2 - M_);
  m = M_;
}

__launch_bounds__(128, 4)
__global__ void k_replay(const float* __restrict__ ws, float* out)
{
  const int c = blockIdx.x;
  long long e0 = (long long)c * CS;
  long long e1 = e0 + CS; if (e1 > NSTEP) e1 = NSTEP;
  const int lane = threadIdx.x & 63;
  const int wv = threadIdx.x >> 6;
  const int x = lane & 15;  // output index (j for alpha, i for beta)
  const int q = lane >> 4;  // quarter: reduces 4 of the 16 contraction terms

  if (wv == 0) {
    // ---------------- alpha (forward) ----------------
    if (c == 0 && lane < 16)
      out[OFF_A + lane] = ws[WS_TR0 + lane] + out[OFF_LPI + lane];
    const float* P = ws + WS_PREF + (size_t)c * 256;
    float v4[4]; float m = NEGINF;
#pragma unroll
    for (int t2 = 0; t2 < 4; t2++) {
      int i2 = 4 * q + t2;
      float a0i = ws[WS_TR0 + i2] + out[OFF_LPI + i2];
      float vv = a0i + P[i2 * 16 + x];
      v4[t2] = vv; m = fmaxf(m, vv);
    }
    float s = 0.f;
#pragma unroll
    for (int t2 = 0; t2 < 4; t2++) s += __expf(v4[t2] - m);
    lse_combine(m, s, 16); lse_combine(m, s, 32);
    float cv = m + __logf(s);
    float vq[4];
#pragma unroll
    for (int t2 = 0; t2 < 4; t2++) vq[t2] = __shfl(cv, q * 4 + t2, 64);

    // prefetch pipeline: [0]=step e0, [1]=step e0+1
    float ta0[4], ta1[4], la0, la1;
#pragma unroll
    for (int t2 = 0; t2 < 4; t2++)
      ta0[t2] = out[OFF_LTR + (size_t)e0 * 256 + (size_t)(4 * q + t2) * 16 + x];
    la0 = out[OFF_LPI + (size_t)(e0 + 1) * 16 + x];
#pragma unroll
    for (int t2 = 0; t2 < 4; t2++)
      ta1[t2] = out[OFF_LTR + (size_t)(e0 + 1) * 256 + (size_t)(4 * q + t2) * 16 + x];
    la1 = out[OFF_LPI + (size_t)(e0 + 2) * 16 + x];

    for (long long e = e0; e < e1; e++) {
      float tn[4], ln;  // prefetch step e+2
#pragma unroll
      for (int t2 = 0; t2 < 4; t2++)
        tn[t2] = out[OFF_LTR + (size_t)(e + 2) * 256 + (size_t)(4 * q + t2) * 16 + x];
      ln = out[OFF_LPI + (size_t)(e + 3) * 16 + x];

      long long t = e + 1;
      float w4[4]; float m2 = NEGINF;
#pragma unroll
      for (int t2 = 0; t2 < 4; t2++) {
        float vvv = vq[t2] + ta0[t2];
        w4[t2] = vvv; m2 = fmaxf(m2, vvv);
      }
      float s2 = 0.f;
#pragma unroll
      for (int t2 = 0; t2 < 4; t2++) s2 += __expf(w4[t2] - m2);
      lse_combine(m2, s2, 16); lse_combine(m2, s2, 32);
      float nv = m2 + __logf(s2) + la0;
      if (lane < 16) out[OFF_A + (size_t)t * 16 + x] = nv;
#pragma unroll
      for (int t2 = 0; t2 < 4; t2++) vq[t2] = __shfl(nv, q * 4 + t2, 64);
#pragma unroll
      for (int t2 = 0; t2 < 4; t2++) { ta0[t2] = ta1[t2]; ta1[t2] = tn[t2]; }
      la0 = la1; la1 = ln;
    }
  } else {
    // ---------------- beta (backward) ----------------
    if (c == NC - 1 && lane < 16) out[OFF_B + (size_t)(T_N - 1) * 16 + lane] = 0.f;
    const float* Sf = ws + WS_SUF + (size_t)c * 256;
    float v4[4]; float m = NEGINF;
#pragma unroll
    for (int t2 = 0; t2 < 4; t2++) {
      float vv = Sf[x * 16 + 4 * q + t2];
      v4[t2] = vv; m = fmaxf(m, vv);
    }
    float s = 0.f;
#pragma unroll
    for (int t2 = 0; t2 < 4; t2++) s += __expf(v4[t2] - m);
    lse_combine(m, s, 16); lse_combine(m, s, 32);
    float u = m + __logf(s);
    float uq[4];
#pragma unroll
    for (int t2 = 0; t2 < 4; t2++) uq[t2] = __shfl(u, q * 4 + t2, 64);

    // prefetch pipeline: [0]=step e1-1, [1]=step e1-2 (signed offsets: stay >= 0)
    float tb0[4], tb1[4], lb0[4], lb1[4];
    {
      long long eA = e1 - 1, eB = e1 - 2;
      float4 f = *(const float4*)&out[(long long)OFF_LTR + eA * 256 + x * 16 + 4 * q];
      tb0[0] = f.x; tb0[1] = f.y; tb0[2] = f.z; tb0[3] = f.w;
      float4 g2 = *(const float4*)&out[(long long)OFF_LPI + (eA + 1) * 16 + 4 * q];
      lb0[0] = g2.x; lb0[1] = g2.y; lb0[2] = g2.z; lb0[3] = g2.w;
      float4 f2 = *(const float4*)&out[(long long)OFF_LTR + eB * 256 + x * 16 + 4 * q];
      tb1[0] = f2.x; tb1[1] = f2.y; tb1[2] = f2.z; tb1[3] = f2.w;
      float4 g3 = *(const float4*)&out[(long long)OFF_LPI + (eB + 1) * 16 + 4 * q];
      lb1[0] = g3.x; lb1[1] = g3.y; lb1[2] = g3.z; lb1[3] = g3.w;
    }

    for (long long e = e1 - 1; e >= e0; e--) {
      float tn[4], ln[4];  // prefetch step e-2 (offset stays >= 0 inside out)
      {
        long long ep = e - 2;
        float4 f = *(const float4*)&out[(long long)OFF_LTR + ep * 256 + x * 16 + 4 * q];
        tn[0] = f.x; tn[1] = f.y; tn[2] = f.z; tn[3] = f.w;
        float4 g2 = *(const float4*)&out[(long long)OFF_LPI + (ep + 1) * 16 + 4 * q];
        ln[0] = g2.x; ln[1] = g2.y; ln[2] = g2.z; ln[3] = g2.w;
      }
      float w4[4]; float m2 = NEGINF;
#pragma unroll
      for (int t2 = 0; t2 < 4; t2++) {
        float vvv = tb0[t2] + lb0[t2] + uq[t2];
        w4[t2] = vvv; m2 = fmaxf(m2, vvv);
      }
      float s2 = 0.f;
#pragma unroll
      for (int t2 = 0; t2 < 4; t2++) s2 += __expf(w4[t2] - m2);
      lse_combine(m2, s2, 16); lse_combine(m2, s2, 32);
      float b = m2 + __logf(s2);
      if (lane < 16) out[OFF_B + (size_t)e * 16 + x] = b;
#pragma unroll
      for (int t2 = 0; t2 < 4; t2++) uq[t2] = __shfl(b, q * 4 + t2, 64);
#pragma unroll
      for (int t2 = 0; t2 < 4; t2++) {
        tb0[t2] = tb1[t2]; tb1[t2] = tn[t2];
        lb0[t2] = lb1[t2]; lb1[t2] = ln[t2];
      }
    }
  }
}

// ------------------------------------------------------------------- launch ---

extern "C" void kernel_launch(void* const* d_in, const int* in_sizes, int n_in,
                              void* d_out, int out_size, void* d_ws, size_t ws_size,
                              hipStream_t stream)
{
  const float* s_array = (const float*)d_in[0];
  const float* a_array = (const float*)d_in[1];
  const float* pW1 = (const float*)d_in[2];
  const float* pb1 = (const float*)d_in[3];
  const float* pW2 = (const float*)d_in[4];
  const float* pb2 = (const float*)d_in[5];
  const float* pW3 = (const float*)d_in[6];
  const float* pb3 = (const float*)d_in[7];
  const float* oW1 = (const float*)d_in[8];
  const float* ob1 = (const float*)d_in[9];
  const float* oW2 = (const float*)d_in[10];
  const float* ob2 = (const float*)d_in[11];
  const float* oW3 = (const float*)d_in[12];
  const float* ob3 = (const float*)d_in[13];
  const float* als = (const float*)d_in[14];
  float* out = (float*)d_out;
  float* ws  = (float*)d_ws;
  ushort_t* wp = (ushort_t*)(ws + WS_WP);

  hipLaunchKernelGGL(k_pack, dim3(64),  dim3(256), 0, stream, pW1, 16384, 16, 256, wp + O_pW1h, wp + O_pW1l);
  hipLaunchKernelGGL(k_pack, dim3(256), dim3(256), 0, stream, pW2, 65536, 16, 256, wp + O_pW2h, wp + O_pW2l);
  hipLaunchKernelGGL(k_pack, dim3(128), dim3(256), 0, stream, pW3, 32768,  8, 128, wp + O_pW3h, wp + O_pW3l);
  hipLaunchKernelGGL(k_pack, dim3(64),  dim3(256), 0, stream, oW1, 16384, 16, 256, wp + O_oW1h, wp + O_oW1l);
  hipLaunchKernelGGL(k_pack, dim3(256), dim3(256), 0, stream, oW2, 65536, 16, 256, wp + O_oW2h, wp + O_oW2l);
  hipLaunchKernelGGL(k_pack, dim3(272), dim3(256), 0, stream, oW3, 69632, 17, 272, wp + O_oW3h, wp + O_oW3l);

  hipLaunchKernelGGL(k_mlp2, dim3(T_N / 32), dim3(256), 0, stream,
                     s_array, a_array, pb1, pb2, pb3, ob1, ob2, ob3, oW3, als,
                     (const ushort_t*)wp, out, ws);
  hipLaunchKernelGGL(k_compose, dim3(NC), dim3(256), 0, stream, out, ws);
  hipLaunchKernelGGL(k_scan_mats, dim3(NG), dim3(256), 0, stream,
                     ws + WS_M, ws + WS_LP, ws + WS_LS, ws + WS_GT);
  hipLaunchKernelGGL(k_scan_mats, dim3(1), dim3(256), 0, stream,
                     ws + WS_GT, ws + WS_GP, ws + WS_GSU, (float*)nullptr);
  hipLaunchKernelGGL(k_combine, dim3(NC), dim3(256), 0, stream, ws);
  hipLaunchKernelGGL(k_replay, dim3(NC), dim3(128), 0, stream, ws, out);
}

// Round 2
// 1515.050 us; speedup vs baseline: 1.0865x; 1.0201x over previous
//
#include <hip/hip_runtime.h>
#include <hip/hip_bf16.h>
#include <math.h>

#define T_N   262144
#define NSTEP (T_N - 1)   // 262143 scan steps

// output layout (floats): log_alpha(T,16) log_beta(T,16) log_trs(T-1,256) log_pis(T,16) entropy(T-1,16)
#define OFF_A   ((size_t)0)
#define OFF_B   ((size_t)4194304)
#define OFF_LTR ((size_t)8388608)
#define OFF_LPI ((size_t)75497216)
#define OFF_ENT ((size_t)79691520)

#define WS_TR0  ((size_t)0)

// packed-weight offsets (ushort units)
#define O_pW1h 0
#define O_pW1l 16384
#define O_pW2h 32768
#define O_pW2l 98304
#define O_pW3h 163840
#define O_pW3l 196608
#define O_oW1h 229376
#define O_oW1l 245760
#define O_oW2h 262144
#define O_oW2l 327680
#define O_oW3h 393216
#define O_oW3l 462848

#define NEGINF (-1e30f)

typedef unsigned short ushort_t;
typedef short s8v __attribute__((ext_vector_type(8)));
typedef float f4v __attribute__((ext_vector_type(4)));

// ---------------------------------------------------------------- configs ---
// Scan geometry: NC2 chunks of CS2 steps; NG2 groups of 32 chunks each.
struct CfgBig   { static constexpr int NC2 = 4096, CS2 = 64,  NG2 = 128; };
struct CfgSmall { static constexpr int NC2 = 1024, CS2 = 256, NG2 = 32;  };

template<class C> struct WSO {
  static constexpr size_t TR0  = 0;
  static constexpr size_t M    = 64;
  static constexpr size_t LP   = M    + (size_t)C::NC2 * 256;
  static constexpr size_t LS   = LP   + (size_t)C::NC2 * 256;
  static constexpr size_t GT   = LS   + (size_t)C::NC2 * 256;
  static constexpr size_t GP   = GT   + (size_t)C::NG2 * 256;
  static constexpr size_t GSU  = GP   + (size_t)C::NG2 * 256;
  static constexpr size_t PREF = GSU  + (size_t)C::NG2 * 256;
  static constexpr size_t SUF  = PREF + (size_t)C::NC2 * 256;
  static constexpr size_t WP   = SUF  + (size_t)C::NC2 * 256;  // bf16 weights (ushort)
  static constexpr size_t TOTAL_BYTES = (WP + 266240 + 64) * 4; // weights = 532480 ushorts
};

__device__ __forceinline__ ushort_t f2bf_rn(float f) {
  __hip_bfloat16 h = __float2bfloat16(f);
  union { __hip_bfloat16 b; ushort_t u; } cv; cv.b = h; return cv.u;
}
__device__ __forceinline__ float us2f(ushort_t u) {
  return __uint_as_float(((unsigned)u) << 16);
}
__device__ __forceinline__ void split_bf(float x, ushort_t& h, ushort_t& lo) {
  unsigned u = __float_as_uint(x);
  h = (ushort_t)(u >> 16);
  lo = f2bf_rn(x - __uint_as_float(u & 0xffff0000u));
}

// ----------------------------------------------------------- weight packing ---
__global__ void k_pack(const float* __restrict__ W, int KN, int NT, int N,
                       ushort_t* __restrict__ dh, ushort_t* __restrict__ dl)
{
  int idx = blockIdx.x * 256 + threadIdx.x;
  if (idx >= KN) return;
  int j  = idx & 7;
  int l  = (idx >> 3) & 63;
  int t2 = idx >> 9;
  int nt = t2 % NT;
  int ks = t2 / NT;
  int k = ks * 32 + (l >> 4) * 8 + j;
  int n = nt * 16 + (l & 15);
  float x = W[(size_t)k * N + n];
  unsigned u = __float_as_uint(x);
  dh[idx] = (ushort_t)(u >> 16);
  dl[idx] = f2bf_rn(x - __uint_as_float(u & 0xffff0000u));
}

// ---------------------------------------------------------------- K1: MLPs ---

#define LDX 72
#define LDH 264

template<int KS, int NTC>
__device__ __forceinline__ void run_layer(const ushort_t* Ah, const ushort_t* Al, int lda,
    const ushort_t* __restrict__ Bh, const ushort_t* __restrict__ Bl, int ntt, int nt0,
    const float* __restrict__ bias, int lane, f4v (&acc)[2][NTC])
{
#pragma unroll
  for (int mt = 0; mt < 2; mt++)
#pragma unroll
    for (int nt = 0; nt < NTC; nt++) {
      float b = bias[(nt0 + nt) * 16 + (lane & 15)];
      acc[mt][nt] = (f4v){b, b, b, b};
    }
  for (int ks = 0; ks < KS; ks++) {
    s8v ah[2], al[2];
#pragma unroll
    for (int mt = 0; mt < 2; mt++) {
      const ushort_t* p = Ah + (size_t)(mt * 16 + (lane & 15)) * lda + ks * 32 + (lane >> 4) * 8;
      ah[mt] = *(const s8v*)p;
      const ushort_t* q = Al + (size_t)(mt * 16 + (lane & 15)) * lda + ks * 32 + (lane >> 4) * 8;
      al[mt] = *(const s8v*)q;
    }
#pragma unroll
    for (int nt = 0; nt < NTC; nt++) {
      size_t bo = ((size_t)(ks * ntt + nt0 + nt) * 64 + lane) * 8;
      s8v bh = *(const s8v*)(Bh + bo);
      s8v bl = *(const s8v*)(Bl + bo);
#pragma unroll
      for (int mt = 0; mt < 2; mt++) {
        acc[mt][nt] = __builtin_amdgcn_mfma_f32_16x16x32_bf16(ah[mt], bh, acc[mt][nt], 0, 0, 0);
        acc[mt][nt] = __builtin_amdgcn_mfma_f32_16x16x32_bf16(al[mt], bh, acc[mt][nt], 0, 0, 0);
        acc[mt][nt] = __builtin_amdgcn_mfma_f32_16x16x32_bf16(ah[mt], bl, acc[mt][nt], 0, 0, 0);
      }
    }
  }
}

__device__ __forceinline__ void store_act(f4v (&acc)[2][4], int nt0, int lane,
                                          ushort_t* Hh, ushort_t* Hl)
{
#pragma unroll
  for (int mt = 0; mt < 2; mt++)
#pragma unroll
    for (int nt = 0; nt < 4; nt++)
#pragma unroll
      for (int r = 0; r < 4; r++) {
        float v = fmaxf(acc[mt][nt][r], 0.f);
        ushort_t h, lo; split_bf(v, h, lo);
        int row = mt * 16 + (lane >> 4) * 4 + r;
        int n = (nt0 + nt) * 16 + (lane & 15);
        Hh[row * LDH + n] = h;
        Hl[row * LDH + n] = lo;
      }
}

__launch_bounds__(256, 3)
__global__ void k_mlp2(const float* __restrict__ s_array, const float* __restrict__ a_array,
                       const float* __restrict__ pb1, const float* __restrict__ pb2,
                       const float* __restrict__ pb3, const float* __restrict__ ob1,
                       const float* __restrict__ ob2, const float* __restrict__ ob3,
                       const float* __restrict__ oW3, const float* __restrict__ als,
                       const ushort_t* __restrict__ wp, float* out, float* ws)
{
  __shared__ ushort_t Xh[32 * LDX], Xl[32 * LDX];
  __shared__ ushort_t Hh[32 * LDH], Hl[32 * LDH];
  __shared__ float tr0s[16];
  const int tid = threadIdx.x;
  const int lane = tid & 63;
  const int w = tid >> 6;
  const size_t row0 = (size_t)blockIdx.x * 32;

  { // stage X (32 rows x 64) into LDS split-bf16, A-frag friendly
    const float4* src = (const float4*)(s_array + row0 * 64);
    for (int f = tid; f < 512; f += 256) {
      float4 v = src[f];
      int r = f >> 4, c = (f & 15) * 4;
      ushort_t h0, l0, h1, l1, h2, l2, h3, l3;
      split_bf(v.x, h0, l0); split_bf(v.y, h1, l1);
      split_bf(v.z, h2, l2); split_bf(v.w, h3, l3);
      ushort4 hh = make_ushort4(h0, h1, h2, h3);
      ushort4 ll = make_ushort4(l0, l1, l2, l3);
      *(ushort4*)&Xh[r * LDX + c] = hh;
      *(ushort4*)&Xl[r * LDX + c] = ll;
    }
  }
  __syncthreads();

  f4v acc[2][4];

  // ===== option net =====
  run_layer<2, 4>(Xh, Xl, LDX, wp + O_oW1h, wp + O_oW1l, 16, w * 4, ob1, lane, acc);
  store_act(acc, w * 4, lane, Hh, Hl);
  __syncthreads();
  run_layer<8, 4>(Hh, Hl, LDH, wp + O_oW2h, wp + O_oW2l, 16, w * 4, ob2, lane, acc);
  __syncthreads();
  store_act(acc, w * 4, lane, Hh, Hl);
  __syncthreads();
  run_layer<8, 4>(Hh, Hl, LDH, wp + O_oW3h, wp + O_oW3l, 17, w * 4, ob3, lane, acc);

  // log-softmax + entropy epilogue (groups == 16-col tiles)
#pragma unroll
  for (int mt = 0; mt < 2; mt++)
#pragma unroll
    for (int nt = 0; nt < 4; nt++) {
      int g = w * 4 + nt;
      int col = lane & 15;
#pragma unroll
      for (int r = 0; r < 4; r++) {
        size_t t = row0 + mt * 16 + (lane >> 4) * 4 + r;
        float x = acc[mt][nt][r];
        float m = x;
        m = fmaxf(m, __shfl_xor(m, 1, 64));
        m = fmaxf(m, __shfl_xor(m, 2, 64));
        m = fmaxf(m, __shfl_xor(m, 4, 64));
        m = fmaxf(m, __shfl_xor(m, 8, 64));
        float s = __expf(x - m);
        s += __shfl_xor(s, 1, 64);
        s += __shfl_xor(s, 2, 64);
        s += __shfl_xor(s, 4, 64);
        s += __shfl_xor(s, 8, 64);
        float L = m + __logf(s);
        float v = x - L;
        float e = -v * __expf(v);
        e += __shfl_xor(e, 1, 64);
        e += __shfl_xor(e, 2, 64);
        e += __shfl_xor(e, 4, 64);
        e += __shfl_xor(e, 8, 64);
        if (t >= 1) {
          out[OFF_LTR + (t - 1) * 256 + (size_t)g * 16 + col] = v;
          if (col == 0) out[OFF_ENT + (t - 1) * 16 + g] = e;
        }
      }
    }

  // log_tr0: row 0's 17th group (block 0 only); H still holds option act2
  if (blockIdx.x == 0 && tid < 16) {
    float a = ob3[256 + tid];
    for (int k2 = 0; k2 < 256; k2++) {
      float hv = us2f(Hh[k2]) + us2f(Hl[k2]);
      a = fmaf(hv, oW3[(size_t)k2 * 272 + 256 + tid], a);
    }
    tr0s[tid] = a;
  }
  __syncthreads();   // also guards H reads (option L3) vs policy L1 writes
  if (blockIdx.x == 0 && tid == 0) {
    float m = NEGINF;
    for (int j = 0; j < 16; j++) m = fmaxf(m, tr0s[j]);
    float s = 0.f;
    for (int j = 0; j < 16; j++) s += __expf(tr0s[j] - m);
    float L = m + __logf(s);
    for (int j = 0; j < 16; j++) ws[WS_TR0 + j] = tr0s[j] - L;
  }

  // ===== policy net =====
  run_layer<2, 4>(Xh, Xl, LDX, wp + O_pW1h, wp + O_pW1l, 16, w * 4, pb1, lane, acc);
  store_act(acc, w * 4, lane, Hh, Hl);
  __syncthreads();
  run_layer<8, 4>(Hh, Hl, LDH, wp + O_pW2h, wp + O_pW2l, 16, w * 4, pb2, lane, acc);
  __syncthreads();
  store_act(acc, w * 4, lane, Hh, Hl);
  __syncthreads();
  f4v pacc[2][2];
  run_layer<8, 2>(Hh, Hl, LDH, wp + O_pW3h, wp + O_pW3l, 8, w * 2, pb3, lane, pacc);

  // gaussian log-prob epilogue
  float istd[8];
  float Kc = -8.0f * 0.91893853320467274f;
#pragma unroll
  for (int a = 0; a < 8; a++) {
    float l = -5.0f + 3.5f * (tanhf(als[a]) + 1.0f);
    istd[a] = __expf(-l);
    Kc -= l;
  }
  int aIdx = lane & 7;
#pragma unroll
  for (int mt = 0; mt < 2; mt++)
#pragma unroll
    for (int nt = 0; nt < 2; nt++) {
      int col = (w * 2 + nt) * 16 + (lane & 15);
      int c = col >> 3;
#pragma unroll
      for (int r = 0; r < 4; r++) {
        size_t t = row0 + mt * 16 + (lane >> 4) * 4 + r;
        float mean = fminf(10.f, fmaxf(-10.f, pacc[mt][nt][r]));
        float av = a_array[t * 8 + aIdx];
        float z = (av - mean) * istd[aIdx];
        float q = z * z;
        q += __shfl_xor(q, 1, 64);
        q += __shfl_xor(q, 2, 64);
        q += __shfl_xor(q, 4, 64);
        if ((lane & 7) == 0) out[OFF_LPI + t * 16 + c] = -0.5f * q + Kc;
      }
    }
}

// ----------------------------------------------- wave-level log-matmul core ---
// Balanced-tree 16-term LSE (all indices compile-time -> registers).
__device__ __forceinline__ float lse16v(const float* v)
{
  float m01 = fmaxf(v[0], v[1]),   m23 = fmaxf(v[2], v[3]);
  float m45 = fmaxf(v[4], v[5]),   m67 = fmaxf(v[6], v[7]);
  float m89 = fmaxf(v[8], v[9]),   mab = fmaxf(v[10], v[11]);
  float mcd = fmaxf(v[12], v[13]), mef = fmaxf(v[14], v[15]);
  float ma = fmaxf(fmaxf(m01, m23), fmaxf(m45, m67));
  float mb = fmaxf(fmaxf(m89, mab), fmaxf(mcd, mef));
  float m = fmaxf(ma, mb);
  float s0 = __expf(v[0] - m) + __expf(v[1] - m);
  float s1 = __expf(v[2] - m) + __expf(v[3] - m);
  float s2 = __expf(v[4] - m) + __expf(v[5] - m);
  float s3 = __expf(v[6] - m) + __expf(v[7] - m);
  float s4 = __expf(v[8] - m) + __expf(v[9] - m);
  float s5 = __expf(v[10] - m) + __expf(v[11] - m);
  float s6 = __expf(v[12] - m) + __expf(v[13] - m);
  float s7 = __expf(v[14] - m) + __expf(v[15] - m);
  float s = ((s0 + s1) + (s2 + s3)) + ((s4 + s5) + (s6 + s7));
  return m + __logf(s);
}

// State-by-rows right-multiply: M <- M o A, then += ls per column.
// lane: i = lane>>2 (state row, replicated over kq), kq = lane&3 (col quarter).
// A: 16x16 row-major floats in LDS. own[] = this lane's 4 new entries.
__device__ __forceinline__ void step_right(float (&Mrow)[16], const float* __restrict__ A,
                                           int lane, float4 ls, float (&own)[4])
{
  const int kq = lane & 3;
  float v0[16], v1[16], v2[16], v3[16];
#pragma unroll
  for (int j = 0; j < 16; j++) {
    float4 a = *(const float4*)(A + j * 16 + kq * 4);  // 4 distinct banks -> conflict-free
    v0[j] = Mrow[j] + a.x;
    v1[j] = Mrow[j] + a.y;
    v2[j] = Mrow[j] + a.z;
    v3[j] = Mrow[j] + a.w;
  }
  float nv0 = lse16v(v0) + ls.x;
  float nv1 = lse16v(v1) + ls.y;
  float nv2 = lse16v(v2) + ls.z;
  float nv3 = lse16v(v3) + ls.w;
  own[0] = nv0; own[1] = nv1; own[2] = nv2; own[3] = nv3;
  const int base = lane & 60;
#pragma unroll
  for (int q2 = 0; q2 < 4; q2++) {
    Mrow[q2 * 4 + 0] = __shfl(nv0, base | q2, 64);
    Mrow[q2 * 4 + 1] = __shfl(nv1, base | q2, 64);
    Mrow[q2 * 4 + 2] = __shfl(nv2, base | q2, 64);
    Mrow[q2 * 4 + 3] = __shfl(nv3, base | q2, 64);
  }
}

// State-by-cols left-multiply: S <- A o S.
// lane: k = lane>>2 (state col, replicated over iq), iq = lane&3 (row quarter).
__device__ __forceinline__ void step_left(float (&Scol)[16], const float* __restrict__ A,
                                          int lane, float (&own)[4])
{
  const int iq = lane & 3;
  float v0[16], v1[16], v2[16], v3[16];
#pragma unroll
  for (int jj = 0; jj < 4; jj++) {
    float4 a0 = *(const float4*)(A + (iq * 4 + 0) * 16 + jj * 4);  // 2-way max -> free
    float4 a1 = *(const float4*)(A + (iq * 4 + 1) * 16 + jj * 4);
    float4 a2 = *(const float4*)(A + (iq * 4 + 2) * 16 + jj * 4);
    float4 a3 = *(const float4*)(A + (iq * 4 + 3) * 16 + jj * 4);
    v0[jj*4+0] = a0.x + Scol[jj*4+0]; v0[jj*4+1] = a0.y + Scol[jj*4+1];
    v0[jj*4+2] = a0.z + Scol[jj*4+2]; v0[jj*4+3] = a0.w + Scol[jj*4+3];
    v1[jj*4+0] = a1.x + Scol[jj*4+0]; v1[jj*4+1] = a1.y + Scol[jj*4+1];
    v1[jj*4+2] = a1.z + Scol[jj*4+2]; v1[jj*4+3] = a1.w + Scol[jj*4+3];
    v2[jj*4+0] = a2.x + Scol[jj*4+0]; v2[jj*4+1] = a2.y + Scol[jj*4+1];
    v2[jj*4+2] = a2.z + Scol[jj*4+2]; v2[jj*4+3] = a2.w + Scol[jj*4+3];
    v3[jj*4+0] = a3.x + Scol[jj*4+0]; v3[jj*4+1] = a3.y + Scol[jj*4+1];
    v3[jj*4+2] = a3.z + Scol[jj*4+2]; v3[jj*4+3] = a3.w + Scol[jj*4+3];
  }
  float nv0 = lse16v(v0);
  float nv1 = lse16v(v1);
  float nv2 = lse16v(v2);
  float nv3 = lse16v(v3);
  own[0] = nv0; own[1] = nv1; own[2] = nv2; own[3] = nv3;
  const int base = lane & 60;
#pragma unroll
  for (int q2 = 0; q2 < 4; q2++) {
    Scol[q2 * 4 + 0] = __shfl(nv0, base | q2, 64);
    Scol[q2 * 4 + 1] = __shfl(nv1, base | q2, 64);
    Scol[q2 * 4 + 2] = __shfl(nv2, base | q2, 64);
    Scol[q2 * 4 + 3] = __shfl(nv3, base | q2, 64);
  }
}

// ------------------------------------------------- K2: per-chunk log-matmul ---
// One wave per chunk, no barriers. Depth-3 register prefetch, per-wave LDS dbuf.
template<class C>
__launch_bounds__(256, 3)
__global__ void k_composeW(const float* __restrict__ out, float* __restrict__ ws)
{
  __shared__ float Abuf[4][2][256] __attribute__((aligned(16)));
  const int tid = threadIdx.x, lane = tid & 63, w = tid >> 6;
  const int kq = lane & 3, i = lane >> 2;
  const long long c = (long long)blockIdx.x * 4 + w;
  long long e0 = c * C::CS2;
  long long e1 = e0 + C::CS2; if (e1 > NSTEP) e1 = NSTEP;

  float Mrow[16], own[4];
#pragma unroll
  for (int j = 0; j < 16; j++) Mrow[j] = (j == i) ? 0.f : NEGINF;
#pragma unroll
  for (int kk = 0; kk < 4; kk++) own[kk] = (kq * 4 + kk == i) ? 0.f : NEGINF;

  const float* LT = out + OFF_LTR;
  const float* LPp = out + OFF_LPI;
  // prefetch pipeline (all over-reads stay inside the out allocation: LTR->LPI->ENT)
  float4 gB = *(const float4*)(LT + e0 * 256 + lane * 4);
  float4 gC = *(const float4*)(LT + (e0 + 1) * 256 + lane * 4);
  float4 lA = *(const float4*)(LPp + (e0 + 1) * 16 + kq * 4);
  float4 lB = *(const float4*)(LPp + (e0 + 2) * 16 + kq * 4);
  float4 lC = *(const float4*)(LPp + (e0 + 3) * 16 + kq * 4);
  *(float4*)(&Abuf[w][0][lane * 4]) = gB;
  gB = gC;
  gC = *(const float4*)(LT + (e0 + 2) * 256 + lane * 4);

  int cur = 0;
  for (long long e = e0; e < e1; e++) {
    float4 gN = *(const float4*)(LT + (e + 3) * 256 + lane * 4);
    float4 lN = *(const float4*)(LPp + (e + 4) * 16 + kq * 4);
    *(float4*)(&Abuf[w][cur ^ 1][lane * 4]) = gB;   // stage step e+1
    step_right(Mrow, &Abuf[w][cur][0], lane, lA, own);
    gB = gC; gC = gN; lA = lB; lB = lC; lC = lN;
    cur ^= 1;
  }
  float4 st; st.x = own[0]; st.y = own[1]; st.z = own[2]; st.w = own[3];
  *(float4*)(ws + WSO<C>::M + (size_t)c * 256 + i * 16 + kq * 4) = st;
}

// ------------------------ K3/K4: group matrix prefix & suffix (wave-parallel) ---
// Block = 4 waves = 2 groups x {fwd, bwd}. No barriers.
template<class C, int LEN>
__launch_bounds__(256, 2)
__global__ void k_scanW(const float* __restrict__ src, float* __restrict__ preDst,
                        float* __restrict__ sufDst, float* __restrict__ totDst, int ngroups)
{
  __shared__ float Abuf[4][2][256] __attribute__((aligned(16)));
  const int tid = threadIdx.x, lane = tid & 63, w = tid >> 6;
  const int grp = blockIdx.x * 2 + (w >> 1);
  const int dir = w & 1;
  if (grp >= ngroups) return;
  const float* S = src + (size_t)grp * LEN * 256;

  if (dir == 0) {
    // forward exclusive prefixes (state by rows)
    const int kq = lane & 3, i = lane >> 2;
    float Mrow[16], own[4];
#pragma unroll
    for (int j = 0; j < 16; j++) Mrow[j] = (j == i) ? 0.f : NEGINF;
#pragma unroll
    for (int kk = 0; kk < 4; kk++) own[kk] = (kq * 4 + kk == i) ? 0.f : NEGINF;
    const float4 zero4 = make_float4(0.f, 0.f, 0.f, 0.f);

    float4 gB = *(const float4*)(S + lane * 4);
    float4 gC = *(const float4*)(S + 256 + lane * 4);
    *(float4*)(&Abuf[w][0][lane * 4]) = gB;
    gB = gC;
    gC = *(const float4*)(S + 2 * 256 + lane * 4);
    int cur = 0;
    for (int r = 0; r < LEN; r++) {
      int rn = (r + 3 < LEN) ? r + 3 : LEN - 1;
      float4 gN = *(const float4*)(S + (size_t)rn * 256 + lane * 4);
      *(float4*)(&Abuf[w][cur ^ 1][lane * 4]) = gB;
      float4 st; st.x = own[0]; st.y = own[1]; st.z = own[2]; st.w = own[3];
      *(float4*)(preDst + ((size_t)grp * LEN + r) * 256 + i * 16 + kq * 4) = st;
      step_right(Mrow, &Abuf[w][cur][0], lane, zero4, own);
      gB = gC; gC = gN; cur ^= 1;
    }
    if (totDst) {
      float4 st; st.x = own[0]; st.y = own[1]; st.z = own[2]; st.w = own[3];
      *(float4*)(totDst + (size_t)grp * 256 + i * 16 + kq * 4) = st;
    }
  } else {
    // backward exclusive suffixes (state by cols)
    const int iq = lane & 3, k = lane >> 2;
    float Scol[16], own[4];
#pragma unroll
    for (int j = 0; j < 16; j++) Scol[j] = (j == k) ? 0.f : NEGINF;
#pragma unroll
    for (int t = 0; t < 4; t++) own[t] = (iq * 4 + t == k) ? 0.f : NEGINF;

    float4 gB = *(const float4*)(S + (size_t)(LEN - 1) * 256 + lane * 4);
    float4 gC = *(const float4*)(S + (size_t)(LEN - 2) * 256 + lane * 4);
    *(float4*)(&Abuf[w][0][lane * 4]) = gB;
    gB = gC;
    gC = *(const float4*)(S + (size_t)(LEN - 3) * 256 + lane * 4);
    int cur = 0;
    for (int r = LEN - 1; r >= 0; r--) {
      int rn = (r - 3 >= 0) ? r - 3 : 0;
      float4 gN = *(const float4*)(S + (size_t)rn * 256 + lane * 4);
      *(float4*)(&Abuf[w][cur ^ 1][lane * 4]) = gB;
      size_t base = ((size_t)grp * LEN + r) * 256;
      sufDst[base + (iq * 4 + 0) * 16 + k] = own[0];
      sufDst[base + (iq * 4 + 1) * 16 + k] = own[1];
      sufDst[base + (iq * 4 + 2) * 16 + k] = own[2];
      sufDst[base + (iq * 4 + 3) * 16 + k] = own[3];
      step_left(Scol, &Abuf[w][cur][0], lane, own);
      gB = gC; gC = gN; cur ^= 1;
    }
  }
}

// ------------------------- K5: chunk-level exclusive prefix/suffix matrices ---
template<class C>
__launch_bounds__(256, 4)
__global__ void k_combine(float* ws)
{
  const int tid = threadIdx.x, i = tid >> 4, k = tid & 15;
  const int c = blockIdx.x, g = c >> 5;
  {
    const float* GP = ws + WSO<C>::GP + (size_t)g * 256;
    const float* LP = ws + WSO<C>::LP + (size_t)c * 256;
    float v[16]; float m = NEGINF;
#pragma unroll
    for (int j = 0; j < 16; j++) { v[j] = GP[i * 16 + j] + LP[j * 16 + k]; m = fmaxf(m, v[j]); }
    float s = 0.f;
#pragma unroll
    for (int j = 0; j < 16; j++) s += __expf(v[j] - m);
    ws[WSO<C>::PREF + (size_t)c * 256 + tid] = m + __logf(s);
  }
  {
    const float* LSu = ws + WSO<C>::LS + (size_t)c * 256;
    const float* GSu = ws + WSO<C>::GSU + (size_t)g * 256;
    float v[16]; float m = NEGINF;
#pragma unroll
    for (int j = 0; j < 16; j++) { v[j] = LSu[i * 16 + j] + GSu[j * 16 + k]; m = fmaxf(m, v[j]); }
    float s = 0.f;
#pragma unroll
    for (int j = 0; j < 16; j++) s += __expf(v[j] - m);
    ws[WSO<C>::SUF + (size_t)c * 256 + tid] = m + __logf(s);
  }
}

// --------------------------------------------------------- K6: chunk replay ---
__device__ __forceinline__ void lse_combine(float& m, float& s, int mask)
{
  float m2 = __shfl_xor(m, mask, 64);
  float s2 = __shfl_xor(s, mask, 64);
  float M_ = fmaxf(m, m2);
  s = s * __expf(m - M_) + s2 * __expf(m2 - M_);
  m = M_;
}

template<class C>
__launch_bounds__(128, 4)
__global__ void k_replay(const float* __restrict__ ws, float* out)
{
  const int c = blockIdx.x;
  long long e0 = (long long)c * C::CS2;
  long long e1 = e0 + C::CS2; if (e1 > NSTEP) e1 = NSTEP;
  const int lane = threadIdx.x & 63;
  const int wv = threadIdx.x >> 6;
  const int x = lane & 15;  // output index (j for alpha, i for beta)
  const int q = lane >> 4;  // quarter: reduces 4 of the 16 contraction terms

  if (wv == 0) {
    // ---------------- alpha (forward) ----------------
    if (c == 0 && lane < 16)
      out[OFF_A + lane] = ws[WSO<C>::TR0 + lane] + out[OFF_LPI + lane];
    const float* P = ws + WSO<C>::PREF + (size_t)c * 256;
    float v4[4]; float m = NEGINF;
#pragma unroll
    for (int t2 = 0; t2 < 4; t2++) {
      int i2 = 4 * q + t2;
      float a0i = ws[WSO<C>::TR0 + i2] + out[OFF_LPI + i2];
      float vv = a0i + P[i2 * 16 + x];
      v4[t2] = vv; m = fmaxf(m, vv);
    }
    float s = 0.f;
#pragma unroll
    for (int t2 = 0; t2 < 4; t2++) s += __expf(v4[t2] - m);
    lse_combine(m, s, 16); lse_combine(m, s, 32);
    float cv = m + __logf(s);
    float vq[4];
#pragma unroll
    for (int t2 = 0; t2 < 4; t2++) vq[t2] = __shfl(cv, q * 4 + t2, 64);

    // prefetch pipeline: [0]=step e0, [1]=step e0+1
    float ta0[4], ta1[4], la0, la1;
#pragma unroll
    for (int t2 = 0; t2 < 4; t2++)
      ta0[t2] = out[OFF_LTR + (size_t)e0 * 256 + (size_t)(4 * q + t2) * 16 + x];
    la0 = out[OFF_LPI + (size_t)(e0 + 1) * 16 + x];
#pragma unroll
    for (int t2 = 0; t2 < 4; t2++)
      ta1[t2] = out[OFF_LTR + (size_t)(e0 + 1) * 256 + (size_t)(4 * q + t2) * 16 + x];
    la1 = out[OFF_LPI + (size_t)(e0 + 2) * 16 + x];

    for (long long e = e0; e < e1; e++) {
      float tn[4], ln;  // prefetch step e+2 (stays inside out allocation)
#pragma unroll
      for (int t2 = 0; t2 < 4; t2++)
        tn[t2] = out[OFF_LTR + (size_t)(e + 2) * 256 + (size_t)(4 * q + t2) * 16 + x];
      ln = out[OFF_LPI + (size_t)(e + 3) * 16 + x];

      long long t = e + 1;
      float w4[4]; float m2 = NEGINF;
#pragma unroll
      for (int t2 = 0; t2 < 4; t2++) {
        float vvv = vq[t2] + ta0[t2];
        w4[t2] = vvv; m2 = fmaxf(m2, vvv);
      }
      float s2 = 0.f;
#pragma unroll
      for (int t2 = 0; t2 < 4; t2++) s2 += __expf(w4[t2] - m2);
      lse_combine(m2, s2, 16); lse_combine(m2, s2, 32);
      float nv = m2 + __logf(s2) + la0;
      if (lane < 16) out[OFF_A + (size_t)t * 16 + x] = nv;
#pragma unroll
      for (int t2 = 0; t2 < 4; t2++) vq[t2] = __shfl(nv, q * 4 + t2, 64);
#pragma unroll
      for (int t2 = 0; t2 < 4; t2++) { ta0[t2] = ta1[t2]; ta1[t2] = tn[t2]; }
      la0 = la1; la1 = ln;
    }
  } else {
    // ---------------- beta (backward) ----------------
    if (c == C::NC2 - 1 && lane < 16) out[OFF_B + (size_t)(T_N - 1) * 16 + lane] = 0.f;
    const float* Sf = ws + WSO<C>::SUF + (size_t)c * 256;
    float v4[4]; float m = NEGINF;
#pragma unroll
    for (int t2 = 0; t2 < 4; t2++) {
      float vv = Sf[x * 16 + 4 * q + t2];
      v4[t2] = vv; m = fmaxf(m, vv);
    }
    float s = 0.f;
#pragma unroll
    for (int t2 = 0; t2 < 4; t2++) s += __expf(v4[t2] - m);
    lse_combine(m, s, 16); lse_combine(m, s, 32);
    float u = m + __logf(s);
    float uq[4];
#pragma unroll
    for (int t2 = 0; t2 < 4; t2++) uq[t2] = __shfl(u, q * 4 + t2, 64);

    // prefetch pipeline: [0]=step e1-1, [1]=step e1-2 (offsets stay >= 0 inside out)
    float tb0[4], tb1[4], lb0[4], lb1[4];
    {
      long long eA = e1 - 1, eB = e1 - 2;
      float4 f = *(const float4*)&out[(long long)OFF_LTR + eA * 256 + x * 16 + 4 * q];
      tb0[0] = f.x; tb0[1] = f.y; tb0[2] = f.z; tb0[3] = f.w;
      float4 g2 = *(const float4*)&out[(long long)OFF_LPI + (eA + 1) * 16 + 4 * q];
      lb0[0] = g2.x; lb0[1] = g2.y; lb0[2] = g2.z; lb0[3] = g2.w;
      float4 f2 = *(const float4*)&out[(long long)OFF_LTR + eB * 256 + x * 16 + 4 * q];
      tb1[0] = f2.x; tb1[1] = f2.y; tb1[2] = f2.z; tb1[3] = f2.w;
      float4 g3 = *(const float4*)&out[(long long)OFF_LPI + (eB + 1) * 16 + 4 * q];
      lb1[0] = g3.x; lb1[1] = g3.y; lb1[2] = g3.z; lb1[3] = g3.w;
    }

    for (long long e = e1 - 1; e >= e0; e--) {
      float tn[4], ln[4];  // prefetch step e-2
      {
        long long ep = e - 2;
        float4 f = *(const float4*)&out[(long long)OFF_LTR + ep * 256 + x * 16 + 4 * q];
        tn[0] = f.x; tn[1] = f.y; tn[2] = f.z; tn[3] = f.w;
        float4 g2 = *(const float4*)&out[(long long)OFF_LPI + (ep + 1) * 16 + 4 * q];
        ln[0] = g2.x; ln[1] = g2.y; ln[2] = g2.z; ln[3] = g2.w;
      }
      float w4[4]; float m2 = NEGINF;
#pragma unroll
      for (int t2 = 0; t2 < 4; t2++) {
        float vvv = tb0[t2] + lb0[t2] + uq[t2];
        w4[t2] = vvv; m2 = fmaxf(m2, vvv);
      }
      float s2 = 0.f;
#pragma unroll
      for (int t2 = 0; t2 < 4; t2++) s2 += __expf(w4[t2] - m2);
      lse_combine(m2, s2, 16); lse_combine(m2, s2, 32);
      float b = m2 + __logf(s2);
      if (lane < 16) out[OFF_B + (size_t)e * 16 + x] = b;
#pragma unroll
      for (int t2 = 0; t2 < 4; t2++) uq[t2] = __shfl(b, q * 4 + t2, 64);
#pragma unroll
      for (int t2 = 0; t2 < 4; t2++) {
        tb0[t2] = tb1[t2]; tb1[t2] = tn[t2];
        lb0[t2] = lb1[t2]; lb1[t2] = ln[t2];
      }
    }
  }
}

// ------------------------------------------------------------------- launch ---

template<class C>
static void launch_all(const float* s_array, const float* a_array,
                       const float* pW1, const float* pb1, const float* pW2, const float* pb2,
                       const float* pW3, const float* pb3, const float* oW1, const float* ob1,
                       const float* oW2, const float* ob2, const float* oW3, const float* ob3,
                       const float* als, float* out, float* ws, hipStream_t stream)
{
  ushort_t* wp = (ushort_t*)(ws + WSO<C>::WP);

  hipLaunchKernelGGL(k_pack, dim3(64),  dim3(256), 0, stream, pW1, 16384, 16, 256, wp + O_pW1h, wp + O_pW1l);
  hipLaunchKernelGGL(k_pack, dim3(256), dim3(256), 0, stream, pW2, 65536, 16, 256, wp + O_pW2h, wp + O_pW2l);
  hipLaunchKernelGGL(k_pack, dim3(128), dim3(256), 0, stream, pW3, 32768,  8, 128, wp + O_pW3h, wp + O_pW3l);
  hipLaunchKernelGGL(k_pack, dim3(64),  dim3(256), 0, stream, oW1, 16384, 16, 256, wp + O_oW1h, wp + O_oW1l);
  hipLaunchKernelGGL(k_pack, dim3(256), dim3(256), 0, stream, oW2, 65536, 16, 256, wp + O_oW2h, wp + O_oW2l);
  hipLaunchKernelGGL(k_pack, dim3(272), dim3(256), 0, stream, oW3, 69632, 17, 272, wp + O_oW3h, wp + O_oW3l);

  hipLaunchKernelGGL(k_mlp2, dim3(T_N / 32), dim3(256), 0, stream,
                     s_array, a_array, pb1, pb2, pb3, ob1, ob2, ob3, oW3, als,
                     (const ushort_t*)wp, out, ws);

  hipLaunchKernelGGL((k_composeW<C>), dim3(C::NC2 / 4), dim3(256), 0, stream, out, ws);
  hipLaunchKernelGGL((k_scanW<C, 32>), dim3(C::NG2 / 2), dim3(256), 0, stream,
                     ws + WSO<C>::M, ws + WSO<C>::LP, ws + WSO<C>::LS, ws + WSO<C>::GT, C::NG2);
  hipLaunchKernelGGL((k_scanW<C, C::NG2>), dim3(1), dim3(128), 0, stream,
                     ws + WSO<C>::GT, ws + WSO<C>::GP, ws + WSO<C>::GSU, (float*)nullptr, 1);
  hipLaunchKernelGGL((k_combine<C>), dim3(C::NC2), dim3(256), 0, stream, ws);
  hipLaunchKernelGGL((k_replay<C>), dim3(C::NC2), dim3(128), 0, stream, ws, out);
}

extern "C" void kernel_launch(void* const* d_in, const int* in_sizes, int n_in,
                              void* d_out, int out_size, void* d_ws, size_t ws_size,
                              hipStream_t stream)
{
  const float* s_array = (const float*)d_in[0];
  const float* a_array = (const float*)d_in[1];
  const float* pW1 = (const float*)d_in[2];
  const float* pb1 = (const float*)d_in[3];
  const float* pW2 = (const float*)d_in[4];
  const float* pb2 = (const float*)d_in[5];
  const float* pW3 = (const float*)d_in[6];
  const float* pb3 = (const float*)d_in[7];
  const float* oW1 = (const float*)d_in[8];
  const float* ob1 = (const float*)d_in[9];
  const float* oW2 = (const float*)d_in[10];
  const float* ob2 = (const float*)d_in[11];
  const float* oW3 = (const float*)d_in[12];
  const float* ob3 = (const float*)d_in[13];
  const float* als = (const float*)d_in[14];
  float* out = (float*)d_out;
  float* ws  = (float*)d_ws;

  if (ws_size >= WSO<CfgBig>::TOTAL_BYTES) {
    launch_all<CfgBig>(s_array, a_array, pW1, pb1, pW2, pb2, pW3, pb3,
                       oW1, ob1, oW2, ob2, oW3, ob3, als, out, ws, stream);
  } else {
    launch_all<CfgSmall>(s_array, a_array, pW1, pb1, pW2, pb2, pW3, pb3,
                         oW1, ob1, oW2, ob2, oW3, ob3, als, out, ws, stream);
  }
}

// Round 3
// 1500.275 us; speedup vs baseline: 1.0972x; 1.0098x over previous
//
#include <hip/hip_runtime.h>
#include <hip/hip_bf16.h>
#include <math.h>

#define T_N   262144
#define NSTEP (T_N - 1)   // 262143 scan steps

// output layout (floats): log_alpha(T,16) log_beta(T,16) log_trs(T-1,256) log_pis(T,16) entropy(T-1,16)
#define OFF_A   ((size_t)0)
#define OFF_B   ((size_t)4194304)
#define OFF_LTR ((size_t)8388608)
#define OFF_LPI ((size_t)75497216)
#define OFF_ENT ((size_t)79691520)

#define WS_TR0  ((size_t)0)

// packed-weight offsets (ushort units)
#define O_pW1h 0
#define O_pW1l 16384
#define O_pW2h 32768
#define O_pW2l 98304
#define O_pW3h 163840
#define O_pW3l 196608
#define O_oW1h 229376
#define O_oW1l 245760
#define O_oW2h 262144
#define O_oW2l 327680
#define O_oW3h 393216
#define O_oW3l 462848

#define NEGINF (-1e30f)

typedef unsigned short ushort_t;
typedef short s8v __attribute__((ext_vector_type(8)));
typedef float f4v __attribute__((ext_vector_type(4)));

// ---------------------------------------------------------------- configs ---
// Scan geometry: NC2 chunks of CS2 steps; NG2 groups of 32 chunks each.
struct CfgBig   { static constexpr int NC2 = 4096, CS2 = 64,  NG2 = 128; };
struct CfgSmall { static constexpr int NC2 = 1024, CS2 = 256, NG2 = 32;  };

template<class C> struct WSO {
  static constexpr size_t TR0  = 0;
  static constexpr size_t M    = 64;
  static constexpr size_t LP   = M    + (size_t)C::NC2 * 256;
  static constexpr size_t LS   = LP   + (size_t)C::NC2 * 256;
  static constexpr size_t GT   = LS   + (size_t)C::NC2 * 256;
  static constexpr size_t GP   = GT   + (size_t)C::NG2 * 256;
  static constexpr size_t GSU  = GP   + (size_t)C::NG2 * 256;
  static constexpr size_t PREF = GSU  + (size_t)C::NG2 * 256;
  static constexpr size_t SUF  = PREF + (size_t)C::NC2 * 256;
  static constexpr size_t WP   = SUF  + (size_t)C::NC2 * 256;  // bf16 weights (ushort)
  static constexpr size_t TOTAL_BYTES = (WP + 266240 + 64) * 4; // weights = 532480 ushorts
};

__device__ __forceinline__ ushort_t f2bf_rn(float f) {
  __hip_bfloat16 h = __float2bfloat16(f);
  union { __hip_bfloat16 b; ushort_t u; } cv; cv.b = h; return cv.u;
}
__device__ __forceinline__ float us2f(ushort_t u) {
  return __uint_as_float(((unsigned)u) << 16);
}
__device__ __forceinline__ void split_bf(float x, ushort_t& h, ushort_t& lo) {
  unsigned u = __float_as_uint(x);
  h = (ushort_t)(u >> 16);
  lo = f2bf_rn(x - __uint_as_float(u & 0xffff0000u));
}

// ----------------------------------------------------------- weight packing ---
__global__ void k_pack(const float* __restrict__ W, int KN, int NT, int N,
                       ushort_t* __restrict__ dh, ushort_t* __restrict__ dl)
{
  int idx = blockIdx.x * 256 + threadIdx.x;
  if (idx >= KN) return;
  int j  = idx & 7;
  int l  = (idx >> 3) & 63;
  int t2 = idx >> 9;
  int nt = t2 % NT;
  int ks = t2 / NT;
  int k = ks * 32 + (l >> 4) * 8 + j;
  int n = nt * 16 + (l & 15);
  float x = W[(size_t)k * N + n];
  unsigned u = __float_as_uint(x);
  dh[idx] = (ushort_t)(u >> 16);
  dl[idx] = f2bf_rn(x - __uint_as_float(u & 0xffff0000u));
}

// ---------------------------------------------------------------- K1: MLPs ---
// 64 rows per block, 512 threads (8 waves), MT=4 row-tiles per wave.
// Halves the per-row L2 weight re-fetch (4096 blocks x 1.04 MB = 4.3 TB)
// and doubles MFMA per B-load (6:1) vs the 32-row version.

#define LDX 72
#define LDH 264

template<int KS, int NTC, int MTt>
__device__ __forceinline__ void run_layer(const ushort_t* Ah, const ushort_t* Al, int lda,
    const ushort_t* __restrict__ Bh, const ushort_t* __restrict__ Bl, int ntt, int nt0,
    const float* __restrict__ bias, int lane, f4v (&acc)[MTt][NTC])
{
#pragma unroll
  for (int mt = 0; mt < MTt; mt++)
#pragma unroll
    for (int nt = 0; nt < NTC; nt++) {
      float b = bias[(nt0 + nt) * 16 + (lane & 15)];
      acc[mt][nt] = (f4v){b, b, b, b};
    }
  for (int ks = 0; ks < KS; ks++) {
    s8v ah[MTt], al[MTt];
#pragma unroll
    for (int mt = 0; mt < MTt; mt++) {
      const ushort_t* p = Ah + (size_t)(mt * 16 + (lane & 15)) * lda + ks * 32 + (lane >> 4) * 8;
      ah[mt] = *(const s8v*)p;
      const ushort_t* q = Al + (size_t)(mt * 16 + (lane & 15)) * lda + ks * 32 + (lane >> 4) * 8;
      al[mt] = *(const s8v*)q;
    }
#pragma unroll
    for (int nt = 0; nt < NTC; nt++) {
      size_t bo = ((size_t)(ks * ntt + nt0 + nt) * 64 + lane) * 8;
      s8v bh = *(const s8v*)(Bh + bo);
      s8v bl = *(const s8v*)(Bl + bo);
#pragma unroll
      for (int mt = 0; mt < MTt; mt++) {
        acc[mt][nt] = __builtin_amdgcn_mfma_f32_16x16x32_bf16(ah[mt], bh, acc[mt][nt], 0, 0, 0);
        acc[mt][nt] = __builtin_amdgcn_mfma_f32_16x16x32_bf16(al[mt], bh, acc[mt][nt], 0, 0, 0);
        acc[mt][nt] = __builtin_amdgcn_mfma_f32_16x16x32_bf16(ah[mt], bl, acc[mt][nt], 0, 0, 0);
      }
    }
  }
}

__device__ __forceinline__ void store_act(f4v (&acc)[4][2], int nt0, int lane,
                                          ushort_t* Hh, ushort_t* Hl)
{
#pragma unroll
  for (int mt = 0; mt < 4; mt++)
#pragma unroll
    for (int nt = 0; nt < 2; nt++)
#pragma unroll
      for (int r = 0; r < 4; r++) {
        float v = fmaxf(acc[mt][nt][r], 0.f);
        ushort_t h, lo; split_bf(v, h, lo);
        int row = mt * 16 + (lane >> 4) * 4 + r;
        int n = (nt0 + nt) * 16 + (lane & 15);
        Hh[row * LDH + n] = h;
        Hl[row * LDH + n] = lo;
      }
}

__launch_bounds__(512)
__global__ void k_mlp2(const float* __restrict__ s_array, const float* __restrict__ a_array,
                       const float* __restrict__ pb1, const float* __restrict__ pb2,
                       const float* __restrict__ pb3, const float* __restrict__ ob1,
                       const float* __restrict__ ob2, const float* __restrict__ ob3,
                       const float* __restrict__ oW3, const float* __restrict__ als,
                       const ushort_t* __restrict__ wp, float* out, float* ws)
{
  __shared__ ushort_t Xh[64 * LDX], Xl[64 * LDX];
  __shared__ ushort_t Hh[64 * LDH], Hl[64 * LDH];
  __shared__ float tr0s[16];
  const int tid = threadIdx.x;
  const int lane = tid & 63;
  const int w = tid >> 6;      // 8 waves
  const size_t row0 = (size_t)blockIdx.x * 64;

  { // stage X (64 rows x 64) into LDS split-bf16, A-frag friendly
    const float4* src = (const float4*)(s_array + row0 * 64);
    for (int f = tid; f < 1024; f += 512) {
      float4 v = src[f];
      int r = f >> 4, c = (f & 15) * 4;
      ushort_t h0, l0, h1, l1, h2, l2, h3, l3;
      split_bf(v.x, h0, l0); split_bf(v.y, h1, l1);
      split_bf(v.z, h2, l2); split_bf(v.w, h3, l3);
      ushort4 hh = make_ushort4(h0, h1, h2, h3);
      ushort4 ll = make_ushort4(l0, l1, l2, l3);
      *(ushort4*)&Xh[r * LDX + c] = hh;
      *(ushort4*)&Xl[r * LDX + c] = ll;
    }
  }
  __syncthreads();

  f4v acc[4][2];

  // ===== option net =====
  run_layer<2, 2, 4>(Xh, Xl, LDX, wp + O_oW1h, wp + O_oW1l, 16, w * 2, ob1, lane, acc);
  store_act(acc, w * 2, lane, Hh, Hl);
  __syncthreads();
  run_layer<8, 2, 4>(Hh, Hl, LDH, wp + O_oW2h, wp + O_oW2l, 16, w * 2, ob2, lane, acc);
  __syncthreads();
  store_act(acc, w * 2, lane, Hh, Hl);
  __syncthreads();
  run_layer<8, 2, 4>(Hh, Hl, LDH, wp + O_oW3h, wp + O_oW3l, 17, w * 2, ob3, lane, acc);

  // log-softmax + entropy epilogue (groups == 16-col tiles)
#pragma unroll
  for (int mt = 0; mt < 4; mt++)
#pragma unroll
    for (int nt = 0; nt < 2; nt++) {
      int g = w * 2 + nt;
      int col = lane & 15;
#pragma unroll
      for (int r = 0; r < 4; r++) {
        size_t t = row0 + mt * 16 + (lane >> 4) * 4 + r;
        float x = acc[mt][nt][r];
        float m = x;
        m = fmaxf(m, __shfl_xor(m, 1, 64));
        m = fmaxf(m, __shfl_xor(m, 2, 64));
        m = fmaxf(m, __shfl_xor(m, 4, 64));
        m = fmaxf(m, __shfl_xor(m, 8, 64));
        float s = __expf(x - m);
        s += __shfl_xor(s, 1, 64);
        s += __shfl_xor(s, 2, 64);
        s += __shfl_xor(s, 4, 64);
        s += __shfl_xor(s, 8, 64);
        float L = m + __logf(s);
        float v = x - L;
        float e = -v * __expf(v);
        e += __shfl_xor(e, 1, 64);
        e += __shfl_xor(e, 2, 64);
        e += __shfl_xor(e, 4, 64);
        e += __shfl_xor(e, 8, 64);
        if (t >= 1) {
          out[OFF_LTR + (t - 1) * 256 + (size_t)g * 16 + col] = v;
          if (col == 0) out[OFF_ENT + (t - 1) * 16 + g] = e;
        }
      }
    }

  // log_tr0: row 0's 17th group (block 0 only); H still holds option act2 (row 0)
  if (blockIdx.x == 0 && tid < 16) {
    float a = ob3[256 + tid];
    for (int k2 = 0; k2 < 256; k2++) {
      float hv = us2f(Hh[k2]) + us2f(Hl[k2]);
      a = fmaf(hv, oW3[(size_t)k2 * 272 + 256 + tid], a);
    }
    tr0s[tid] = a;
  }
  __syncthreads();   // also guards H reads (option L3) vs policy L1 writes
  if (blockIdx.x == 0 && tid == 0) {
    float m = NEGINF;
    for (int j = 0; j < 16; j++) m = fmaxf(m, tr0s[j]);
    float s = 0.f;
    for (int j = 0; j < 16; j++) s += __expf(tr0s[j] - m);
    float L = m + __logf(s);
    for (int j = 0; j < 16; j++) ws[WS_TR0 + j] = tr0s[j] - L;
  }

  // ===== policy net =====
  run_layer<2, 2, 4>(Xh, Xl, LDX, wp + O_pW1h, wp + O_pW1l, 16, w * 2, pb1, lane, acc);
  store_act(acc, w * 2, lane, Hh, Hl);
  __syncthreads();
  run_layer<8, 2, 4>(Hh, Hl, LDH, wp + O_pW2h, wp + O_pW2l, 16, w * 2, pb2, lane, acc);
  __syncthreads();
  store_act(acc, w * 2, lane, Hh, Hl);
  __syncthreads();
  f4v pacc[4][1];
  run_layer<8, 1, 4>(Hh, Hl, LDH, wp + O_pW3h, wp + O_pW3l, 8, w, pb3, lane, pacc);

  // gaussian log-prob epilogue
  float istd[8];
  float Kc = -8.0f * 0.91893853320467274f;
#pragma unroll
  for (int a = 0; a < 8; a++) {
    float l = -5.0f + 3.5f * (tanhf(als[a]) + 1.0f);
    istd[a] = __expf(-l);
    Kc -= l;
  }
  int aIdx = lane & 7;
#pragma unroll
  for (int mt = 0; mt < 4; mt++) {
    int col = w * 16 + (lane & 15);
    int c = col >> 3;
#pragma unroll
    for (int r = 0; r < 4; r++) {
      size_t t = row0 + mt * 16 + (lane >> 4) * 4 + r;
      float mean = fminf(10.f, fmaxf(-10.f, pacc[mt][0][r]));
      float av = a_array[t * 8 + aIdx];
      float z = (av - mean) * istd[aIdx];
      float q = z * z;
      q += __shfl_xor(q, 1, 64);
      q += __shfl_xor(q, 2, 64);
      q += __shfl_xor(q, 4, 64);
      if ((lane & 7) == 0) out[OFF_LPI + t * 16 + c] = -0.5f * q + Kc;
    }
  }
}

// ----------------------------------------------- wave-level log-matmul core ---
// Balanced-tree 16-term LSE (all indices compile-time -> registers).
__device__ __forceinline__ float lse16v(const float* v)
{
  float m01 = fmaxf(v[0], v[1]),   m23 = fmaxf(v[2], v[3]);
  float m45 = fmaxf(v[4], v[5]),   m67 = fmaxf(v[6], v[7]);
  float m89 = fmaxf(v[8], v[9]),   mab = fmaxf(v[10], v[11]);
  float mcd = fmaxf(v[12], v[13]), mef = fmaxf(v[14], v[15]);
  float ma = fmaxf(fmaxf(m01, m23), fmaxf(m45, m67));
  float mb = fmaxf(fmaxf(m89, mab), fmaxf(mcd, mef));
  float m = fmaxf(ma, mb);
  float s0 = __expf(v[0] - m) + __expf(v[1] - m);
  float s1 = __expf(v[2] - m) + __expf(v[3] - m);
  float s2 = __expf(v[4] - m) + __expf(v[5] - m);
  float s3 = __expf(v[6] - m) + __expf(v[7] - m);
  float s4 = __expf(v[8] - m) + __expf(v[9] - m);
  float s5 = __expf(v[10] - m) + __expf(v[11] - m);
  float s6 = __expf(v[12] - m) + __expf(v[13] - m);
  float s7 = __expf(v[14] - m) + __expf(v[15] - m);
  float s = ((s0 + s1) + (s2 + s3)) + ((s4 + s5) + (s6 + s7));
  return m + __logf(s);
}

// State-by-rows right-multiply: M <- M o A, then += ls per column.
__device__ __forceinline__ void step_right(float (&Mrow)[16], const float* __restrict__ A,
                                           int lane, float4 ls, float (&own)[4])
{
  const int kq = lane & 3;
  float v0[16], v1[16], v2[16], v3[16];
#pragma unroll
  for (int j = 0; j < 16; j++) {
    float4 a = *(const float4*)(A + j * 16 + kq * 4);  // broadcast-friendly
    v0[j] = Mrow[j] + a.x;
    v1[j] = Mrow[j] + a.y;
    v2[j] = Mrow[j] + a.z;
    v3[j] = Mrow[j] + a.w;
  }
  float nv0 = lse16v(v0) + ls.x;
  float nv1 = lse16v(v1) + ls.y;
  float nv2 = lse16v(v2) + ls.z;
  float nv3 = lse16v(v3) + ls.w;
  own[0] = nv0; own[1] = nv1; own[2] = nv2; own[3] = nv3;
  const int base = lane & 60;
#pragma unroll
  for (int q2 = 0; q2 < 4; q2++) {
    Mrow[q2 * 4 + 0] = __shfl(nv0, base | q2, 64);
    Mrow[q2 * 4 + 1] = __shfl(nv1, base | q2, 64);
    Mrow[q2 * 4 + 2] = __shfl(nv2, base | q2, 64);
    Mrow[q2 * 4 + 3] = __shfl(nv3, base | q2, 64);
  }
}

// State-by-cols left-multiply: S <- A o S.
__device__ __forceinline__ void step_left(float (&Scol)[16], const float* __restrict__ A,
                                          int lane, float (&own)[4])
{
  const int iq = lane & 3;
  float v0[16], v1[16], v2[16], v3[16];
#pragma unroll
  for (int jj = 0; jj < 4; jj++) {
    float4 a0 = *(const float4*)(A + (iq * 4 + 0) * 16 + jj * 4);
    float4 a1 = *(const float4*)(A + (iq * 4 + 1) * 16 + jj * 4);
    float4 a2 = *(const float4*)(A + (iq * 4 + 2) * 16 + jj * 4);
    float4 a3 = *(const float4*)(A + (iq * 4 + 3) * 16 + jj * 4);
    v0[jj*4+0] = a0.x + Scol[jj*4+0]; v0[jj*4+1] = a0.y + Scol[jj*4+1];
    v0[jj*4+2] = a0.z + Scol[jj*4+2]; v0[jj*4+3] = a0.w + Scol[jj*4+3];
    v1[jj*4+0] = a1.x + Scol[jj*4+0]; v1[jj*4+1] = a1.y + Scol[jj*4+1];
    v1[jj*4+2] = a1.z + Scol[jj*4+2]; v1[jj*4+3] = a1.w + Scol[jj*4+3];
    v2[jj*4+0] = a2.x + Scol[jj*4+0]; v2[jj*4+1] = a2.y + Scol[jj*4+1];
    v2[jj*4+2] = a2.z + Scol[jj*4+2]; v2[jj*4+3] = a2.w + Scol[jj*4+3];
    v3[jj*4+0] = a3.x + Scol[jj*4+0]; v3[jj*4+1] = a3.y + Scol[jj*4+1];
    v3[jj*4+2] = a3.z + Scol[jj*4+2]; v3[jj*4+3] = a3.w + Scol[jj*4+3];
  }
  float nv0 = lse16v(v0);
  float nv1 = lse16v(v1);
  float nv2 = lse16v(v2);
  float nv3 = lse16v(v3);
  own[0] = nv0; own[1] = nv1; own[2] = nv2; own[3] = nv3;
  const int base = lane & 60;
#pragma unroll
  for (int q2 = 0; q2 < 4; q2++) {
    Scol[q2 * 4 + 0] = __shfl(nv0, base | q2, 64);
    Scol[q2 * 4 + 1] = __shfl(nv1, base | q2, 64);
    Scol[q2 * 4 + 2] = __shfl(nv2, base | q2, 64);
    Scol[q2 * 4 + 3] = __shfl(nv3, base | q2, 64);
  }
}

// ------------------------------------------------- K2: per-chunk log-matmul ---
template<class C>
__launch_bounds__(256, 3)
__global__ void k_composeW(const float* __restrict__ out, float* __restrict__ ws)
{
  __shared__ float Abuf[4][2][256] __attribute__((aligned(16)));
  const int tid = threadIdx.x, lane = tid & 63, w = tid >> 6;
  const int kq = lane & 3, i = lane >> 2;
  const long long c = (long long)blockIdx.x * 4 + w;
  long long e0 = c * C::CS2;
  long long e1 = e0 + C::CS2; if (e1 > NSTEP) e1 = NSTEP;

  float Mrow[16], own[4];
#pragma unroll
  for (int j = 0; j < 16; j++) Mrow[j] = (j == i) ? 0.f : NEGINF;
#pragma unroll
  for (int kk = 0; kk < 4; kk++) own[kk] = (kq * 4 + kk == i) ? 0.f : NEGINF;

  const float* LT = out + OFF_LTR;
  const float* LPp = out + OFF_LPI;
  float4 gB = *(const float4*)(LT + e0 * 256 + lane * 4);
  float4 gC = *(const float4*)(LT + (e0 + 1) * 256 + lane * 4);
  float4 lA = *(const float4*)(LPp + (e0 + 1) * 16 + kq * 4);
  float4 lB = *(const float4*)(LPp + (e0 + 2) * 16 + kq * 4);
  float4 lC = *(const float4*)(LPp + (e0 + 3) * 16 + kq * 4);
  *(float4*)(&Abuf[w][0][lane * 4]) = gB;
  gB = gC;
  gC = *(const float4*)(LT + (e0 + 2) * 256 + lane * 4);

  int cur = 0;
  for (long long e = e0; e < e1; e++) {
    float4 gN = *(const float4*)(LT + (e + 3) * 256 + lane * 4);
    float4 lN = *(const float4*)(LPp + (e + 4) * 16 + kq * 4);
    *(float4*)(&Abuf[w][cur ^ 1][lane * 4]) = gB;   // stage step e+1
    step_right(Mrow, &Abuf[w][cur][0], lane, lA, own);
    gB = gC; gC = gN; lA = lB; lB = lC; lC = lN;
    cur ^= 1;
  }
  float4 st; st.x = own[0]; st.y = own[1]; st.z = own[2]; st.w = own[3];
  *(float4*)(ws + WSO<C>::M + (size_t)c * 256 + i * 16 + kq * 4) = st;
}

// ------------------------ K3/K4: group matrix prefix & suffix (wave-parallel) ---
template<class C, int LEN>
__launch_bounds__(256, 2)
__global__ void k_scanW(const float* __restrict__ src, float* __restrict__ preDst,
                        float* __restrict__ sufDst, float* __restrict__ totDst, int ngroups)
{
  __shared__ float Abuf[4][2][256] __attribute__((aligned(16)));
  const int tid = threadIdx.x, lane = tid & 63, w = tid >> 6;
  const int grp = blockIdx.x * 2 + (w >> 1);
  const int dir = w & 1;
  if (grp >= ngroups) return;
  const float* S = src + (size_t)grp * LEN * 256;

  if (dir == 0) {
    const int kq = lane & 3, i = lane >> 2;
    float Mrow[16], own[4];
#pragma unroll
    for (int j = 0; j < 16; j++) Mrow[j] = (j == i) ? 0.f : NEGINF;
#pragma unroll
    for (int kk = 0; kk < 4; kk++) own[kk] = (kq * 4 + kk == i) ? 0.f : NEGINF;
    const float4 zero4 = make_float4(0.f, 0.f, 0.f, 0.f);

    float4 gB = *(const float4*)(S + lane * 4);
    float4 gC = *(const float4*)(S + 256 + lane * 4);
    *(float4*)(&Abuf[w][0][lane * 4]) = gB;
    gB = gC;
    gC = *(const float4*)(S + 2 * 256 + lane * 4);
    int cur = 0;
    for (int r = 0; r < LEN; r++) {
      int rn = (r + 3 < LEN) ? r + 3 : LEN - 1;
      float4 gN = *(const float4*)(S + (size_t)rn * 256 + lane * 4);
      *(float4*)(&Abuf[w][cur ^ 1][lane * 4]) = gB;
      float4 st; st.x = own[0]; st.y = own[1]; st.z = own[2]; st.w = own[3];
      *(float4*)(preDst + ((size_t)grp * LEN + r) * 256 + i * 16 + kq * 4) = st;
      step_right(Mrow, &Abuf[w][cur][0], lane, zero4, own);
      gB = gC; gC = gN; cur ^= 1;
    }
    if (totDst) {
      float4 st; st.x = own[0]; st.y = own[1]; st.z = own[2]; st.w = own[3];
      *(float4*)(totDst + (size_t)grp * 256 + i * 16 + kq * 4) = st;
    }
  } else {
    const int iq = lane & 3, k = lane >> 2;
    float Scol[16], own[4];
#pragma unroll
    for (int j = 0; j < 16; j++) Scol[j] = (j == k) ? 0.f : NEGINF;
#pragma unroll
    for (int t = 0; t < 4; t++) own[t] = (iq * 4 + t == k) ? 0.f : NEGINF;

    float4 gB = *(const float4*)(S + (size_t)(LEN - 1) * 256 + lane * 4);
    float4 gC = *(const float4*)(S + (size_t)(LEN - 2) * 256 + lane * 4);
    *(float4*)(&Abuf[w][0][lane * 4]) = gB;
    gB = gC;
    gC = *(const float4*)(S + (size_t)(LEN - 3) * 256 + lane * 4);
    int cur = 0;
    for (int r = LEN - 1; r >= 0; r--) {
      int rn = (r - 3 >= 0) ? r - 3 : 0;
      float4 gN = *(const float4*)(S + (size_t)rn * 256 + lane * 4);
      *(float4*)(&Abuf[w][cur ^ 1][lane * 4]) = gB;
      size_t base = ((size_t)grp * LEN + r) * 256;
      sufDst[base + (iq * 4 + 0) * 16 + k] = own[0];
      sufDst[base + (iq * 4 + 1) * 16 + k] = own[1];
      sufDst[base + (iq * 4 + 2) * 16 + k] = own[2];
      sufDst[base + (iq * 4 + 3) * 16 + k] = own[3];
      step_left(Scol, &Abuf[w][cur][0], lane, own);
      gB = gC; gC = gN; cur ^= 1;
    }
  }
}

// ------------------------- K5: chunk-level exclusive prefix/suffix matrices ---
template<class C>
__launch_bounds__(256, 4)
__global__ void k_combine(float* ws)
{
  const int tid = threadIdx.x, i = tid >> 4, k = tid & 15;
  const int c = blockIdx.x, g = c >> 5;
  {
    const float* GP = ws + WSO<C>::GP + (size_t)g * 256;
    const float* LP = ws + WSO<C>::LP + (size_t)c * 256;
    float v[16]; float m = NEGINF;
#pragma unroll
    for (int j = 0; j < 16; j++) { v[j] = GP[i * 16 + j] + LP[j * 16 + k]; m = fmaxf(m, v[j]); }
    float s = 0.f;
#pragma unroll
    for (int j = 0; j < 16; j++) s += __expf(v[j] - m);
    ws[WSO<C>::PREF + (size_t)c * 256 + tid] = m + __logf(s);
  }
  {
    const float* LSu = ws + WSO<C>::LS + (size_t)c * 256;
    const float* GSu = ws + WSO<C>::GSU + (size_t)g * 256;
    float v[16]; float m = NEGINF;
#pragma unroll
    for (int j = 0; j < 16; j++) { v[j] = LSu[i * 16 + j] + GSu[j * 16 + k]; m = fmaxf(m, v[j]); }
    float s = 0.f;
#pragma unroll
    for (int j = 0; j < 16; j++) s += __expf(v[j] - m);
    ws[WSO<C>::SUF + (size_t)c * 256 + tid] = m + __logf(s);
  }
}

// --------------------------------------------------------- K6: chunk replay ---
__device__ __forceinline__ void lse_combine(float& m, float& s, int mask)
{
  float m2 = __shfl_xor(m, mask, 64);
  float s2 = __shfl_xor(s, mask, 64);
  float M_ = fmaxf(m, m2);
  s = s * __expf(m - M_) + s2 * __expf(m2 - M_);
  m = M_;
}

template<class C>
__launch_bounds__(128, 4)
__global__ void k_replay(const float* __restrict__ ws, float* out)
{
  const int c = blockIdx.x;
  long long e0 = (long long)c * C::CS2;
  long long e1 = e0 + C::CS2; if (e1 > NSTEP) e1 = NSTEP;
  const int lane = threadIdx.x & 63;
  const int wv = threadIdx.x >> 6;
  const int x = lane & 15;
  const int q = lane >> 4;

  if (wv == 0) {
    // ---------------- alpha (forward) ----------------
    if (c == 0 && lane < 16)
      out[OFF_A + lane] = ws[WSO<C>::TR0 + lane] + out[OFF_LPI + lane];
    const float* P = ws + WSO<C>::PREF + (size_t)c * 256;
    float v4[4]; float m = NEGINF;
#pragma unroll
    for (int t2 = 0; t2 < 4; t2++) {
      int i2 = 4 * q + t2;
      float a0i = ws[WSO<C>::TR0 + i2] + out[OFF_LPI + i2];
      float vv = a0i + P[i2 * 16 + x];
      v4[t2] = vv; m = fmaxf(m, vv);
    }
    float s = 0.f;
#pragma unroll
    for (int t2 = 0; t2 < 4; t2++) s += __expf(v4[t2] - m);
    lse_combine(m, s, 16); lse_combine(m, s, 32);
    float cv = m + __logf(s);
    float vq[4];
#pragma unroll
    for (int t2 = 0; t2 < 4; t2++) vq[t2] = __shfl(cv, q * 4 + t2, 64);

    float ta0[4], ta1[4], la0, la1;
#pragma unroll
    for (int t2 = 0; t2 < 4; t2++)
      ta0[t2] = out[OFF_LTR + (size_t)e0 * 256 + (size_t)(4 * q + t2) * 16 + x];
    la0 = out[OFF_LPI + (size_t)(e0 + 1) * 16 + x];
#pragma unroll
    for (int t2 = 0; t2 < 4; t2++)
      ta1[t2] = out[OFF_LTR + (size_t)(e0 + 1) * 256 + (size_t)(4 * q + t2) * 16 + x];
    la1 = out[OFF_LPI + (size_t)(e0 + 2) * 16 + x];

    for (long long e = e0; e < e1; e++) {
      float tn[4], ln;
#pragma unroll
      for (int t2 = 0; t2 < 4; t2++)
        tn[t2] = out[OFF_LTR + (size_t)(e + 2) * 256 + (size_t)(4 * q + t2) * 16 + x];
      ln = out[OFF_LPI + (size_t)(e + 3) * 16 + x];

      long long t = e + 1;
      float w4[4]; float m2 = NEGINF;
#pragma unroll
      for (int t2 = 0; t2 < 4; t2++) {
        float vvv = vq[t2] + ta0[t2];
        w4[t2] = vvv; m2 = fmaxf(m2, vvv);
      }
      float s2 = 0.f;
#pragma unroll
      for (int t2 = 0; t2 < 4; t2++) s2 += __expf(w4[t2] - m2);
      lse_combine(m2, s2, 16); lse_combine(m2, s2, 32);
      float nv = m2 + __logf(s2) + la0;
      if (lane < 16) out[OFF_A + (size_t)t * 16 + x] = nv;
#pragma unroll
      for (int t2 = 0; t2 < 4; t2++) vq[t2] = __shfl(nv, q * 4 + t2, 64);
#pragma unroll
      for (int t2 = 0; t2 < 4; t2++) { ta0[t2] = ta1[t2]; ta1[t2] = tn[t2]; }
      la0 = la1; la1 = ln;
    }
  } else {
    // ---------------- beta (backward) ----------------
    if (c == C::NC2 - 1 && lane < 16) out[OFF_B + (size_t)(T_N - 1) * 16 + lane] = 0.f;
    const float* Sf = ws + WSO<C>::SUF + (size_t)c * 256;
    float v4[4]; float m = NEGINF;
#pragma unroll
    for (int t2 = 0; t2 < 4; t2++) {
      float vv = Sf[x * 16 + 4 * q + t2];
      v4[t2] = vv; m = fmaxf(m, vv);
    }
    float s = 0.f;
#pragma unroll
    for (int t2 = 0; t2 < 4; t2++) s += __expf(v4[t2] - m);
    lse_combine(m, s, 16); lse_combine(m, s, 32);
    float u = m + __logf(s);
    float uq[4];
#pragma unroll
    for (int t2 = 0; t2 < 4; t2++) uq[t2] = __shfl(u, q * 4 + t2, 64);

    float tb0[4], tb1[4], lb0[4], lb1[4];
    {
      long long eA = e1 - 1, eB = e1 - 2;
      float4 f = *(const float4*)&out[(long long)OFF_LTR + eA * 256 + x * 16 + 4 * q];
      tb0[0] = f.x; tb0[1] = f.y; tb0[2] = f.z; tb0[3] = f.w;
      float4 g2 = *(const float4*)&out[(long long)OFF_LPI + (eA + 1) * 16 + 4 * q];
      lb0[0] = g2.x; lb0[1] = g2.y; lb0[2] = g2.z; lb0[3] = g2.w;
      float4 f2 = *(const float4*)&out[(long long)OFF_LTR + eB * 256 + x * 16 + 4 * q];
      tb1[0] = f2.x; tb1[1] = f2.y; tb1[2] = f2.z; tb1[3] = f2.w;
      float4 g3 = *(const float4*)&out[(long long)OFF_LPI + (eB + 1) * 16 + 4 * q];
      lb1[0] = g3.x; lb1[1] = g3.y; lb1[2] = g3.z; lb1[3] = g3.w;
    }

    for (long long e = e1 - 1; e >= e0; e--) {
      float tn[4], ln[4];
      {
        long long ep = e - 2;
        float4 f = *(const float4*)&out[(long long)OFF_LTR + ep * 256 + x * 16 + 4 * q];
        tn[0] = f.x; tn[1] = f.y; tn[2] = f.z; tn[3] = f.w;
        float4 g2 = *(const float4*)&out[(long long)OFF_LPI + (ep + 1) * 16 + 4 * q];
        ln[0] = g2.x; ln[1] = g2.y; ln[2] = g2.z; ln[3] = g2.w;
      }
      float w4[4]; float m2 = NEGINF;
#pragma unroll
      for (int t2 = 0; t2 < 4; t2++) {
        float vvv = tb0[t2] + lb0[t2] + uq[t2];
        w4[t2] = vvv; m2 = fmaxf(m2, vvv);
      }
      float s2 = 0.f;
#pragma unroll
      for (int t2 = 0; t2 < 4; t2++) s2 += __expf(w4[t2] - m2);
      lse_combine(m2, s2, 16); lse_combine(m2, s2, 32);
      float b = m2 + __logf(s2);
      if (lane < 16) out[OFF_B + (size_t)e * 16 + x] = b;
#pragma unroll
      for (int t2 = 0; t2 < 4; t2++) uq[t2] = __shfl(b, q * 4 + t2, 64);
#pragma unroll
      for (int t2 = 0; t2 < 4; t2++) {
        tb0[t2] = tb1[t2]; tb1[t2] = tn[t2];
        lb0[t2] = lb1[t2]; lb1[t2] = ln[t2];
      }
    }
  }
}

// ------------------------------------------------------------------- launch ---

template<class C>
static void launch_all(const float* s_array, const float* a_array,
                       const float* pW1, const float* pb1, const float* pW2, const float* pb2,
                       const float* pW3, const float* pb3, const float* oW1, const float* ob1,
                       const float* oW2, const float* ob2, const float* oW3, const float* ob3,
                       const float* als, float* out, float* ws, hipStream_t stream)
{
  ushort_t* wp = (ushort_t*)(ws + WSO<C>::WP);

  hipLaunchKernelGGL(k_pack, dim3(64),  dim3(256), 0, stream, pW1, 16384, 16, 256, wp + O_pW1h, wp + O_pW1l);
  hipLaunchKernelGGL(k_pack, dim3(256), dim3(256), 0, stream, pW2, 65536, 16, 256, wp + O_pW2h, wp + O_pW2l);
  hipLaunchKernelGGL(k_pack, dim3(128), dim3(256), 0, stream, pW3, 32768,  8, 128, wp + O_pW3h, wp + O_pW3l);
  hipLaunchKernelGGL(k_pack, dim3(64),  dim3(256), 0, stream, oW1, 16384, 16, 256, wp + O_oW1h, wp + O_oW1l);
  hipLaunchKernelGGL(k_pack, dim3(256), dim3(256), 0, stream, oW2, 65536, 16, 256, wp + O_oW2h, wp + O_oW2l);
  hipLaunchKernelGGL(k_pack, dim3(272), dim3(256), 0, stream, oW3, 69632, 17, 272, wp + O_oW3h, wp + O_oW3l);

  hipLaunchKernelGGL(k_mlp2, dim3(T_N / 64), dim3(512), 0, stream,
                     s_array, a_array, pb1, pb2, pb3, ob1, ob2, ob3, oW3, als,
                     (const ushort_t*)wp, out, ws);

  hipLaunchKernelGGL((k_composeW<C>), dim3(C::NC2 / 4), dim3(256), 0, stream, out, ws);
  hipLaunchKernelGGL((k_scanW<C, 32>), dim3(C::NG2 / 2), dim3(256), 0, stream,
                     ws + WSO<C>::M, ws + WSO<C>::LP, ws + WSO<C>::LS, ws + WSO<C>::GT, C::NG2);
  hipLaunchKernelGGL((k_scanW<C, C::NG2>), dim3(1), dim3(128), 0, stream,
                     ws + WSO<C>::GT, ws + WSO<C>::GP, ws + WSO<C>::GSU, (float*)nullptr, 1);
  hipLaunchKernelGGL((k_combine<C>), dim3(C::NC2), dim3(256), 0, stream, ws);
  hipLaunchKernelGGL((k_replay<C>), dim3(C::NC2), dim3(128), 0, stream, ws, out);
}

extern "C" void kernel_launch(void* const* d_in, const int* in_sizes, int n_in,
                              void* d_out, int out_size, void* d_ws, size_t ws_size,
                              hipStream_t stream)
{
  const float* s_array = (const float*)d_in[0];
  const float* a_array = (const float*)d_in[1];
  const float* pW1 = (const float*)d_in[2];
  const float* pb1 = (const float*)d_in[3];
  const float* pW2 = (const float*)d_in[4];
  const float* pb2 = (const float*)d_in[5];
  const float* pW3 = (const float*)d_in[6];
  const float* pb3 = (const float*)d_in[7];
  const float* oW1 = (const float*)d_in[8];
  const float* ob1 = (const float*)d_in[9];
  const float* oW2 = (const float*)d_in[10];
  const float* ob2 = (const float*)d_in[11];
  const float* oW3 = (const float*)d_in[12];
  const float* ob3 = (const float*)d_in[13];
  const float* als = (const float*)d_in[14];
  float* out = (float*)d_out;
  float* ws  = (float*)d_ws;

  if (ws_size >= WSO<CfgBig>::TOTAL_BYTES) {
    launch_all<CfgBig>(s_array, a_array, pW1, pb1, pW2, pb2, pW3, pb3,
                       oW1, ob1, oW2, ob2, oW3, ob3, als, out, ws, stream);
  } else {
    launch_all<CfgSmall>(s_array, a_array, pW1, pb1, pW2, pb2, pW3, pb3,
                         oW1, ob1, oW2, ob2, oW3, ob3, als, out, ws, stream);
  }
}